// Round 1
// baseline (261.528 us; speedup 1.0000x reference)
//
#include <hip/hip_runtime.h>
#include <hip/hip_bf16.h>
#include <math.h>

// ---- types ----
typedef __bf16 bf16_t;
typedef bf16_t bf16x8 __attribute__((ext_vector_type(8)));
typedef float f32x4 __attribute__((ext_vector_type(4)));

#define D_MODEL 1024
#define NH 16
#define DK 64
#define SEQ 2048
#define MROWS 4096   // B*S
#define LDSW 64      // UNPADDED row width for async-DMA tiles (XOR-swizzled)
#define LDC 136      // padded row for the 128x128 epilogue staging tile

__device__ __forceinline__ bf16x8 ldfrag(const bf16_t* p) {
    union { uint4 u; bf16x8 v; } c;
    c.u = *reinterpret_cast<const uint4*>(p);
    return c.v;
}

__device__ __forceinline__ f32x4 zero4() { f32x4 z = {0.f, 0.f, 0.f, 0.f}; return z; }

// async global->LDS DMA, 16B per lane. LDS dest = wave-uniform base + lane*16.
__device__ __forceinline__ void gll16(const bf16_t* g, bf16_t* l) {
    __builtin_amdgcn_global_load_lds(
        (const __attribute__((address_space(1))) unsigned int*)g,
        (__attribute__((address_space(3))) unsigned int*)l,
        16, 0, 0);
}

// ---- fp32 -> bf16 pack, 3 tensors via blockIdx.y ----
__global__ void pack3(const float* __restrict__ a, const float* __restrict__ b,
                      const float* __restrict__ c,
                      bf16_t* __restrict__ da, bf16_t* __restrict__ db, bf16_t* __restrict__ dc) {
    const float* s = (blockIdx.y == 0) ? a : (blockIdx.y == 1) ? b : c;
    bf16_t* d      = (blockIdx.y == 0) ? da : (blockIdx.y == 1) ? db : dc;
    int i = (blockIdx.x * blockDim.x + threadIdx.x) * 4;
    float4 f = *reinterpret_cast<const float4*>(s + i);
    union { bf16_t h[4]; uint2 u; } o;
    o.h[0] = (bf16_t)f.x; o.h[1] = (bf16_t)f.y; o.h[2] = (bf16_t)f.z; o.h[3] = (bf16_t)f.w;
    *reinterpret_cast<uint2*>(d + i) = o.u;
}

// ---- fp32 -> bf16 pack, 4 weight matrices via blockIdx.y ----
__global__ void pack4(const float* __restrict__ a, const float* __restrict__ b,
                      const float* __restrict__ c, const float* __restrict__ e,
                      bf16_t* __restrict__ da, bf16_t* __restrict__ db,
                      bf16_t* __restrict__ dc, bf16_t* __restrict__ de) {
    const float* s = (blockIdx.y == 0) ? a : (blockIdx.y == 1) ? b : (blockIdx.y == 2) ? c : e;
    bf16_t* d      = (blockIdx.y == 0) ? da : (blockIdx.y == 1) ? db : (blockIdx.y == 2) ? dc : de;
    int i = (blockIdx.x * blockDim.x + threadIdx.x) * 4;
    float4 f = *reinterpret_cast<const float4*>(s + i);
    union { bf16_t h[4]; uint2 u; } o;
    o.h[0] = (bf16_t)f.x; o.h[1] = (bf16_t)f.y; o.h[2] = (bf16_t)f.z; o.h[3] = (bf16_t)f.w;
    *reinterpret_cast<uint2*>(d + i) = o.u;
}

// ---- shared GEMM core: C(128x128) = A(rowmaj MxK) * B(rowmaj NxK)^T ----
// m97 structure: async global_load_lds staging; unpadded [128][64] tiles with
// XOR 16B-chunk swizzle (phys chunk p of row r holds logical chunk p^(r&7)).
__device__ __forceinline__ void gemm_core(
    const bf16_t* __restrict__ A, const bf16_t* __restrict__ Bm,
    int K, int m0, int n0,
    bf16_t* As, bf16_t* Bs,       // each 128*LDSW bf16
    f32x4 acc[4][4]) {

    const int tid = threadIdx.x;
    const int lane = tid & 63;
    const int wid = tid >> 6;
    const int wm = (wid >> 1) * 64, wn = (wid & 1) * 64;
    const int l15 = lane & 15, quad = lane >> 4;

    const int lrow   = lane >> 3;                // 0..7 row within 8-row group
    const int gcol   = ((lane & 7) ^ lrow) * 8;  // swizzled logical col (elems)

    #pragma unroll
    for (int i = 0; i < 4; i++)
        #pragma unroll
        for (int j = 0; j < 4; j++) acc[i][j] = zero4();

    for (int k0 = 0; k0 < K; k0 += 64) {
        __syncthreads();
        #pragma unroll
        for (int t = 0; t < 4; t++) {
            const int rbase = wid * 32 + t * 8;
            gll16(A  + (size_t)(m0 + rbase + lrow) * K + k0 + gcol, As + rbase * LDSW);
            gll16(Bm + (size_t)(n0 + rbase + lrow) * K + k0 + gcol, Bs + rbase * LDSW);
        }
        __syncthreads();
        #pragma unroll
        for (int c = 0; c < 2; c++) {
            bf16x8 af[4], bfr[4];
            #pragma unroll
            for (int i = 0; i < 4; i++) {
                const int row = wm + i * 16 + l15;
                const int pc = ((c * 4 + quad) ^ (l15 & 7)) * 8;
                af[i] = ldfrag(As + row * LDSW + pc);
            }
            #pragma unroll
            for (int j = 0; j < 4; j++) {
                const int row = wn + j * 16 + l15;
                const int pc = ((c * 4 + quad) ^ (l15 & 7)) * 8;
                bfr[j] = ldfrag(Bs + row * LDSW + pc);
            }
            #pragma unroll
            for (int i = 0; i < 4; i++)
                #pragma unroll
                for (int j = 0; j < 4; j++)
                    acc[i][j] = __builtin_amdgcn_mfma_f32_16x16x32_bf16(af[i], bfr[j], acc[i][j], 0, 0, 0);
        }
    }
}

// ---- fused Q/K/V projection: blockIdx.z picks which ----
__global__ __launch_bounds__(256, 2) void proj_gemm(
    const bf16_t* __restrict__ qb, const bf16_t* __restrict__ kb,
    const bf16_t* __restrict__ vb,
    const bf16_t* __restrict__ Wq, const bf16_t* __restrict__ Wk,
    const bf16_t* __restrict__ Wv,
    const float* __restrict__ bq, const float* __restrict__ bk, const float* __restrict__ bv,
    bf16_t* __restrict__ Qh, bf16_t* __restrict__ Kh, bf16_t* __restrict__ Vt) {

    __shared__ __align__(16) bf16_t sm[128 * LDC];   // 34816B: As|Bs, reused as Cs
    bf16_t* As = sm;
    bf16_t* Bs = sm + 128 * LDSW;
    bf16_t (*Cs)[LDC] = reinterpret_cast<bf16_t(*)[LDC]>(sm);
    f32x4 acc[4][4];

    const int mode = blockIdx.z;
    const bf16_t* X = (mode == 0) ? qb : (mode == 1) ? kb : vb;
    const bf16_t* W = (mode == 0) ? Wq : (mode == 1) ? Wk : Wv;
    const float* bias = (mode == 0) ? bq : (mode == 1) ? bk : bv;
    const int m0 = blockIdx.y * 128, n0 = blockIdx.x * 128;

    gemm_core(X, W, D_MODEL, m0, n0, As, Bs, acc);

    const int tid = threadIdx.x, lane = tid & 63, wid = tid >> 6;
    const int wm = (wid >> 1) * 64, wn = (wid & 1) * 64;
    const int l15 = lane & 15, quad = lane >> 4;

    __syncthreads();
    if (mode != 2) {
        // Q gets 1/sqrt(dk) * log2(e) folded in so attn can use raw exp2
        const float sc = (mode == 0) ? 0.125f * 1.44269504f : 1.0f;
        #pragma unroll
        for (int i = 0; i < 4; i++)
            #pragma unroll
            for (int j = 0; j < 4; j++)
                #pragma unroll
                for (int r = 0; r < 4; r++) {
                    int gn = n0 + wn + j * 16 + l15;
                    Cs[wm + i * 16 + quad * 4 + r][wn + j * 16 + l15] =
                        (bf16_t)((acc[i][j][r] + bias[gn]) * sc);
                }
    } else {
        #pragma unroll
        for (int i = 0; i < 4; i++)
            #pragma unroll
            for (int j = 0; j < 4; j++)
                #pragma unroll
                for (int r = 0; r < 4; r++) {
                    int gn = n0 + wn + j * 16 + l15;
                    Cs[wn + j * 16 + l15][wm + i * 16 + quad * 4 + r] =
                        (bf16_t)(acc[i][j][r] + bias[gn]);
                }
    }
    __syncthreads();

    #pragma unroll
    for (int c = tid; c < 2048; c += 256) {
        int row = c >> 4, col8 = (c & 15) << 3;
        uint4 val = *reinterpret_cast<const uint4*>(&Cs[row][col8]);
        if (mode != 2) {
            int gm = m0 + row, gn = n0 + col8;
            int b = gm >> 11, seq = gm & 2047;
            int h = gn >> 6, dk = gn & 63;
            bf16_t* dst = (mode == 0) ? Qh : Kh;
            *reinterpret_cast<uint4*>(dst + ((size_t)(b * NH + h) * SEQ + seq) * DK + dk) = val;
        } else {
            int gn = n0 + row, gm = m0 + col8;
            int b = gm >> 11, seq = gm & 2047;
            int h = gn >> 6, dk = gn & 63;
            *reinterpret_cast<uint4*>(Vt + ((size_t)(b * NH + h) * DK + dk) * SEQ + seq) = val;
        }
    }
}

// ---- output projection: fp32 out + bias ----
__global__ __launch_bounds__(256, 2) void out_gemm(
    const bf16_t* __restrict__ Oc, const bf16_t* __restrict__ Wo,
    const float* __restrict__ bo, float* __restrict__ Cout) {

    __shared__ __align__(16) bf16_t As[128 * LDSW];
    __shared__ __align__(16) bf16_t Bs[128 * LDSW];
    f32x4 acc[4][4];
    const int m0 = blockIdx.y * 128, n0 = blockIdx.x * 128;

    gemm_core(Oc, Wo, D_MODEL, m0, n0, As, Bs, acc);

    const int tid = threadIdx.x, lane = tid & 63, wid = tid >> 6;
    const int wm = (wid >> 1) * 64, wn = (wid & 1) * 64;
    const int l15 = lane & 15, quad = lane >> 4;

    #pragma unroll
    for (int i = 0; i < 4; i++)
        #pragma unroll
        for (int j = 0; j < 4; j++)
            #pragma unroll
            for (int r = 0; r < 4; r++) {
                int gm = m0 + wm + i * 16 + quad * 4 + r;
                int gn = n0 + wn + j * 16 + l15;
                Cout[(size_t)gm * D_MODEL + gn] = acc[i][j][r] + bo[gn];
            }
}

// ---- flash attention: one block = one (b,h) x 64-query tile; 64-key tiles ----
// R10: double-buffered K/V staging with raw s_barrier + counted vmcnt(4) so
// the next tile's DMAs stay in flight across the barrier (no vmcnt(0) drain
// per tile — that drain was the ~25% stall at MfmaUtil 16.5%). P round-trip
// tile switched from padded LDP=72 (8-way bank alias on the b128 read) to
// unpadded [64][64] with the same XOR-chunk swizzle as K/V (uniform banks).
// LDS = 2*8K (K) + 2*8K (V) + 8K (P) = 40960B -> still exactly 4 blocks/CU.
__global__ __launch_bounds__(256) void attn_kernel(
    const bf16_t* __restrict__ Qh, const bf16_t* __restrict__ Kh,
    const bf16_t* __restrict__ Vt, bf16_t* __restrict__ Oc) {

    __shared__ __align__(16) bf16_t Ks[2][64 * LDSW];    // K tiles [key][dk], swizzled
    __shared__ __align__(16) bf16_t Vts[2][64 * LDSW];   // V^T tiles [dk][key], swizzled
    __shared__ __align__(16) bf16_t Pls[64 * LDSW];      // P / O-epilogue, swizzled

    const int tid = threadIdx.x, lane = tid & 63, wid = tid >> 6;
    const int l15 = lane & 15, quad = lane >> 4;
    const int bh = blockIdx.x;                 // XCD-friendly
    const int q0 = blockIdx.y * 64;
    const bf16_t* Qbase = Qh + (size_t)bh * SEQ * DK;
    const bf16_t* Kbase = Kh + (size_t)bh * SEQ * DK;
    const bf16_t* Vbase = Vt + (size_t)bh * DK * SEQ;

    const int lrow = lane >> 3;                  // 0..7 row within 8-row group
    const int gcol = ((lane & 7) ^ lrow) * 8;    // swizzled logical col (elems)

    // Q fragments: wave wid owns query rows [q0+wid*16, +16)
    bf16x8 aQ[2];
    #pragma unroll
    for (int c = 0; c < 2; c++)
        aQ[c] = ldfrag(Qbase + (size_t)(q0 + wid * 16 + l15) * DK + c * 32 + quad * 8);

    f32x4 oacc[4];
    #pragma unroll
    for (int j = 0; j < 4; j++) oacc[j] = zero4();
    float l_i[4] = {0.f, 0.f, 0.f, 0.f};

    // prologue: stage tile 0 into buffer 0 (4 DMA insts per wave)
    #pragma unroll
    for (int t = 0; t < 2; t++) {
        const int rbase = wid * 16 + t * 8;
        gll16(Kbase + (size_t)(rbase + lrow) * DK + gcol,  Ks[0]  + rbase * LDSW);
        gll16(Vbase + (size_t)(rbase + lrow) * SEQ + gcol, Vts[0] + rbase * LDSW);
    }

    const int pch = l15 >> 3, pwi = l15 & 7;     // P-write chunk/within-chunk

    for (int kt = 0; kt < SEQ / 64; kt++) {
        const int buf = kt & 1;
        const int nkt = (kt + 1 < SEQ / 64) ? kt + 1 : kt;   // clamp: last iter re-stages (harmless)
        const int nk0 = nkt * 64;

        // stage tile kt+1 into buf^1 (writes the buffer everyone finished
        // reading at BAR2 of iteration kt-1 — race-free)
        #pragma unroll
        for (int t = 0; t < 2; t++) {
            const int rbase = wid * 16 + t * 8;
            gll16(Kbase + (size_t)(nk0 + rbase + lrow) * DK + gcol,  Ks[buf ^ 1]  + rbase * LDSW);
            gll16(Vbase + (size_t)(rbase + lrow) * SEQ + nk0 + gcol, Vts[buf ^ 1] + rbase * LDSW);
        }
        // my own 4 newest DMAs are tile kt+1; wait until only those remain ->
        // tile kt's 4 DMAs (and any older loads) are done. BAR1 then makes
        // that true for all 4 waves. No vmcnt(0) drain anywhere in the loop.
        asm volatile("s_waitcnt vmcnt(4)" ::: "memory");
        __builtin_amdgcn_s_barrier();
        __builtin_amdgcn_sched_barrier(0);

        const bf16_t* Kb = Ks[buf];
        const bf16_t* Vb = Vts[buf];

        // S = Q*K^T (Q pre-scaled by log2e/8)
        f32x4 sacc[4];
        #pragma unroll
        for (int j = 0; j < 4; j++) sacc[j] = zero4();
        __builtin_amdgcn_s_setprio(1);
        #pragma unroll
        for (int c = 0; c < 2; c++) {
            bf16x8 bk4[4];
            #pragma unroll
            for (int j = 0; j < 4; j++) {
                const int pc = ((c * 4 + quad) ^ (l15 & 7)) * 8;
                bk4[j] = ldfrag(Kb + (j * 16 + l15) * LDSW + pc);
            }
            #pragma unroll
            for (int j = 0; j < 4; j++)
                sacc[j] = __builtin_amdgcn_mfma_f32_16x16x32_bf16(
                    aQ[c], bk4[j], sacc[j], 0, 0, 0);
        }
        __builtin_amdgcn_s_setprio(0);

        // exp2, partial row sums, P -> wave-private LDS rows (swizzled chunks)
        #pragma unroll
        for (int r = 0; r < 4; r++) {
            float e0 = exp2f(sacc[0][r]);
            float e1 = exp2f(sacc[1][r]);
            float e2 = exp2f(sacc[2][r]);
            float e3 = exp2f(sacc[3][r]);
            l_i[r] += (e0 + e1) + (e2 + e3);
            bf16_t* prow = Pls + (wid * 16 + quad * 4 + r) * LDSW;
            const int rx = (quad * 4 + r) & 7;
            prow[((pch    ) ^ rx) * 8 + pwi] = (bf16_t)e0;
            prow[((pch + 2) ^ rx) * 8 + pwi] = (bf16_t)e1;
            prow[((pch + 4) ^ rx) * 8 + pwi] = (bf16_t)e2;
            prow[((pch + 6) ^ rx) * 8 + pwi] = (bf16_t)e3;
        }

        // O += P*V (same-wave LDS write->read; compiler inserts lgkmcnt wait)
        __builtin_amdgcn_s_setprio(1);
        #pragma unroll
        for (int c = 0; c < 2; c++) {
            bf16x8 ap = ldfrag(Pls + (wid * 16 + l15) * LDSW +
                               (((c * 4 + quad) ^ (l15 & 7)) << 3));
            bf16x8 bv4[4];
            #pragma unroll
            for (int j = 0; j < 4; j++) {
                const int pc = ((c * 4 + quad) ^ (l15 & 7)) * 8;
                bv4[j] = ldfrag(Vb + (j * 16 + l15) * LDSW + pc);
            }
            #pragma unroll
            for (int j = 0; j < 4; j++)
                oacc[j] = __builtin_amdgcn_mfma_f32_16x16x32_bf16(
                    ap, bv4[j], oacc[j], 0, 0, 0);
        }
        __builtin_amdgcn_s_setprio(0);

        // all waves done reading buf before iter kt+2 DMAs into it
        __builtin_amdgcn_s_barrier();
    }

    // normalize, stage into Pls (swizzled), then coalesced 16B stores
    #pragma unroll
    for (int r = 0; r < 4; r++) {
        float l = l_i[r];
        #pragma unroll
        for (int off = 1; off < 16; off <<= 1)
            l += __shfl_xor(l, off, 64);
        float inv = 1.0f / l;
        bf16_t* prow = Pls + (wid * 16 + quad * 4 + r) * LDSW;
        const int rx = (quad * 4 + r) & 7;
        #pragma unroll
        for (int j = 0; j < 4; j++)
            prow[((pch + 2 * j) ^ rx) * 8 + pwi] = (bf16_t)(oacc[j][r] * inv);
    }
    __syncthreads();

    const int b = bh >> 4, h = bh & 15;
    #pragma unroll
    for (int c = tid; c < 512; c += 256) {   // 64 rows x 8 chunks of 8 bf16
        int row = c >> 3, chunk = c & 7;
        uint4 val = *reinterpret_cast<const uint4*>(
            Pls + row * LDSW + ((chunk ^ (row & 7)) << 3));
        *reinterpret_cast<uint4*>(Oc + ((size_t)(b * SEQ + q0 + row)) * D_MODEL + h * DK + (chunk << 3)) = val;
    }
}

extern "C" void kernel_launch(void* const* d_in, const int* in_sizes, int n_in,
                              void* d_out, int out_size, void* d_ws, size_t ws_size,
                              hipStream_t stream) {
    const float* q  = (const float*)d_in[0];
    const float* k  = (const float*)d_in[1];
    const float* v  = (const float*)d_in[2];
    const float* Wq = (const float*)d_in[3];
    const float* bq = (const float*)d_in[4];
    const float* Wk = (const float*)d_in[5];
    const float* bk = (const float*)d_in[6];
    const float* Wv = (const float*)d_in[7];
    const float* bv = (const float*)d_in[8];
    const float* Wo = (const float*)d_in[9];
    const float* bo = (const float*)d_in[10];

    const size_t nx = (size_t)MROWS * D_MODEL;   // 4,194,304
    const size_t nw = (size_t)D_MODEL * D_MODEL; // 1,048,576

    bf16_t* qb  = (bf16_t*)d_ws;
    bf16_t* kb  = qb  + nx;
    bf16_t* vb  = kb  + nx;
    bf16_t* Wqb = vb  + nx;
    bf16_t* Wkb = Wqb + nw;
    bf16_t* Wvb = Wkb + nw;
    bf16_t* Wob = Wvb + nw;
    bf16_t* Qh  = Wob + nw;   // [BH][S][DK]
    bf16_t* Kh  = Qh  + nx;   // [BH][S][DK]
    bf16_t* Vt  = Kh  + nx;   // [BH][DK][S]
    bf16_t* Oc  = Vt  + nx;   // [B*S][D]

    pack3<<<dim3(4096, 3), 256, 0, stream>>>(q, k, v, qb, kb, vb);
    pack4<<<dim3(1024, 4), 256, 0, stream>>>(Wq, Wk, Wv, Wo, Wqb, Wkb, Wvb, Wob);

    proj_gemm<<<dim3(8, 32, 3), 256, 0, stream>>>(qb, kb, vb, Wqb, Wkb, Wvb, bq, bk, bv, Qh, Kh, Vt);
    attn_kernel<<<dim3(32, 32), 256, 0, stream>>>(Qh, Kh, Vt, Oc);
    out_gemm<<<dim3(8, 32), 256, 0, stream>>>(Oc, Wob, bo, (float*)d_out);
}

// Round 3
// 258.307 us; speedup vs baseline: 1.0125x; 1.0125x over previous
//
#include <hip/hip_runtime.h>
#include <hip/hip_bf16.h>
#include <math.h>

// ---- types ----
typedef __bf16 bf16_t;
typedef bf16_t bf16x8 __attribute__((ext_vector_type(8)));
typedef float f32x4 __attribute__((ext_vector_type(4)));

#define D_MODEL 1024
#define NH 16
#define DK 64
#define SEQ 2048
#define MROWS 4096   // B*S
#define LDSW 64      // UNPADDED row width for async-DMA tiles (XOR-swizzled)
#define LDC 136      // padded row for the 128x128 epilogue staging tile

__device__ __forceinline__ bf16x8 ldfrag(const bf16_t* p) {
    union { uint4 u; bf16x8 v; } c;
    c.u = *reinterpret_cast<const uint4*>(p);
    return c.v;
}

__device__ __forceinline__ f32x4 zero4() { f32x4 z = {0.f, 0.f, 0.f, 0.f}; return z; }

// async global->LDS DMA, 16B per lane. LDS dest = wave-uniform base + lane*16.
__device__ __forceinline__ void gll16(const bf16_t* g, bf16_t* l) {
    __builtin_amdgcn_global_load_lds(
        (const __attribute__((address_space(1))) unsigned int*)g,
        (__attribute__((address_space(3))) unsigned int*)l,
        16, 0, 0);
}

// ---- fp32 -> bf16 pack, 3 tensors via blockIdx.y ----
__global__ void pack3(const float* __restrict__ a, const float* __restrict__ b,
                      const float* __restrict__ c,
                      bf16_t* __restrict__ da, bf16_t* __restrict__ db, bf16_t* __restrict__ dc) {
    const float* s = (blockIdx.y == 0) ? a : (blockIdx.y == 1) ? b : c;
    bf16_t* d      = (blockIdx.y == 0) ? da : (blockIdx.y == 1) ? db : dc;
    int i = (blockIdx.x * blockDim.x + threadIdx.x) * 4;
    float4 f = *reinterpret_cast<const float4*>(s + i);
    union { bf16_t h[4]; uint2 u; } o;
    o.h[0] = (bf16_t)f.x; o.h[1] = (bf16_t)f.y; o.h[2] = (bf16_t)f.z; o.h[3] = (bf16_t)f.w;
    *reinterpret_cast<uint2*>(d + i) = o.u;
}

// ---- fp32 -> bf16 pack, 4 weight matrices via blockIdx.y ----
__global__ void pack4(const float* __restrict__ a, const float* __restrict__ b,
                      const float* __restrict__ c, const float* __restrict__ e,
                      bf16_t* __restrict__ da, bf16_t* __restrict__ db,
                      bf16_t* __restrict__ dc, bf16_t* __restrict__ de) {
    const float* s = (blockIdx.y == 0) ? a : (blockIdx.y == 1) ? b : (blockIdx.y == 2) ? c : e;
    bf16_t* d      = (blockIdx.y == 0) ? da : (blockIdx.y == 1) ? db : (blockIdx.y == 2) ? dc : de;
    int i = (blockIdx.x * blockDim.x + threadIdx.x) * 4;
    float4 f = *reinterpret_cast<const float4*>(s + i);
    union { bf16_t h[4]; uint2 u; } o;
    o.h[0] = (bf16_t)f.x; o.h[1] = (bf16_t)f.y; o.h[2] = (bf16_t)f.z; o.h[3] = (bf16_t)f.w;
    *reinterpret_cast<uint2*>(d + i) = o.u;
}

// ---- shared GEMM core: C(128x128) = A(rowmaj MxK) * B(rowmaj NxK)^T ----
// m97 structure: async global_load_lds staging; unpadded [128][64] tiles with
// XOR 16B-chunk swizzle (phys chunk p of row r holds logical chunk p^(r&7)).
__device__ __forceinline__ void gemm_core(
    const bf16_t* __restrict__ A, const bf16_t* __restrict__ Bm,
    int K, int m0, int n0,
    bf16_t* As, bf16_t* Bs,       // each 128*LDSW bf16
    f32x4 acc[4][4]) {

    const int tid = threadIdx.x;
    const int lane = tid & 63;
    const int wid = tid >> 6;
    const int wm = (wid >> 1) * 64, wn = (wid & 1) * 64;
    const int l15 = lane & 15, quad = lane >> 4;

    const int lrow   = lane >> 3;                // 0..7 row within 8-row group
    const int gcol   = ((lane & 7) ^ lrow) * 8;  // swizzled logical col (elems)

    #pragma unroll
    for (int i = 0; i < 4; i++)
        #pragma unroll
        for (int j = 0; j < 4; j++) acc[i][j] = zero4();

    for (int k0 = 0; k0 < K; k0 += 64) {
        __syncthreads();
        #pragma unroll
        for (int t = 0; t < 4; t++) {
            const int rbase = wid * 32 + t * 8;
            gll16(A  + (size_t)(m0 + rbase + lrow) * K + k0 + gcol, As + rbase * LDSW);
            gll16(Bm + (size_t)(n0 + rbase + lrow) * K + k0 + gcol, Bs + rbase * LDSW);
        }
        __syncthreads();
        #pragma unroll
        for (int c = 0; c < 2; c++) {
            bf16x8 af[4], bfr[4];
            #pragma unroll
            for (int i = 0; i < 4; i++) {
                const int row = wm + i * 16 + l15;
                const int pc = ((c * 4 + quad) ^ (l15 & 7)) * 8;
                af[i] = ldfrag(As + row * LDSW + pc);
            }
            #pragma unroll
            for (int j = 0; j < 4; j++) {
                const int row = wn + j * 16 + l15;
                const int pc = ((c * 4 + quad) ^ (l15 & 7)) * 8;
                bfr[j] = ldfrag(Bs + row * LDSW + pc);
            }
            #pragma unroll
            for (int i = 0; i < 4; i++)
                #pragma unroll
                for (int j = 0; j < 4; j++)
                    acc[i][j] = __builtin_amdgcn_mfma_f32_16x16x32_bf16(af[i], bfr[j], acc[i][j], 0, 0, 0);
        }
    }
}

// ---- fused Q/K/V projection: blockIdx.z picks which ----
__global__ __launch_bounds__(256, 2) void proj_gemm(
    const bf16_t* __restrict__ qb, const bf16_t* __restrict__ kb,
    const bf16_t* __restrict__ vb,
    const bf16_t* __restrict__ Wq, const bf16_t* __restrict__ Wk,
    const bf16_t* __restrict__ Wv,
    const float* __restrict__ bq, const float* __restrict__ bk, const float* __restrict__ bv,
    bf16_t* __restrict__ Qh, bf16_t* __restrict__ Kh, bf16_t* __restrict__ Vt) {

    __shared__ __align__(16) bf16_t sm[128 * LDC];   // 34816B: As|Bs, reused as Cs
    bf16_t* As = sm;
    bf16_t* Bs = sm + 128 * LDSW;
    bf16_t (*Cs)[LDC] = reinterpret_cast<bf16_t(*)[LDC]>(sm);
    f32x4 acc[4][4];

    const int mode = blockIdx.z;
    const bf16_t* X = (mode == 0) ? qb : (mode == 1) ? kb : vb;
    const bf16_t* W = (mode == 0) ? Wq : (mode == 1) ? Wk : Wv;
    const float* bias = (mode == 0) ? bq : (mode == 1) ? bk : bv;
    const int m0 = blockIdx.y * 128, n0 = blockIdx.x * 128;

    gemm_core(X, W, D_MODEL, m0, n0, As, Bs, acc);

    const int tid = threadIdx.x, lane = tid & 63, wid = tid >> 6;
    const int wm = (wid >> 1) * 64, wn = (wid & 1) * 64;
    const int l15 = lane & 15, quad = lane >> 4;

    __syncthreads();
    if (mode != 2) {
        // Q gets 1/sqrt(dk) * log2(e) folded in so attn can use raw exp2
        const float sc = (mode == 0) ? 0.125f * 1.44269504f : 1.0f;
        #pragma unroll
        for (int i = 0; i < 4; i++)
            #pragma unroll
            for (int j = 0; j < 4; j++)
                #pragma unroll
                for (int r = 0; r < 4; r++) {
                    int gn = n0 + wn + j * 16 + l15;
                    Cs[wm + i * 16 + quad * 4 + r][wn + j * 16 + l15] =
                        (bf16_t)((acc[i][j][r] + bias[gn]) * sc);
                }
    } else {
        #pragma unroll
        for (int i = 0; i < 4; i++)
            #pragma unroll
            for (int j = 0; j < 4; j++)
                #pragma unroll
                for (int r = 0; r < 4; r++) {
                    int gn = n0 + wn + j * 16 + l15;
                    Cs[wn + j * 16 + l15][wm + i * 16 + quad * 4 + r] =
                        (bf16_t)(acc[i][j][r] + bias[gn]);
                }
    }
    __syncthreads();

    #pragma unroll
    for (int c = tid; c < 2048; c += 256) {
        int row = c >> 4, col8 = (c & 15) << 3;
        uint4 val = *reinterpret_cast<const uint4*>(&Cs[row][col8]);
        if (mode != 2) {
            int gm = m0 + row, gn = n0 + col8;
            int b = gm >> 11, seq = gm & 2047;
            int h = gn >> 6, dk = gn & 63;
            bf16_t* dst = (mode == 0) ? Qh : Kh;
            *reinterpret_cast<uint4*>(dst + ((size_t)(b * NH + h) * SEQ + seq) * DK + dk) = val;
        } else {
            int gn = n0 + row, gm = m0 + col8;
            int b = gm >> 11, seq = gm & 2047;
            int h = gn >> 6, dk = gn & 63;
            *reinterpret_cast<uint4*>(Vt + ((size_t)(b * NH + h) * DK + dk) * SEQ + seq) = val;
        }
    }
}

// ---- output projection: fp32 out + bias ----
__global__ __launch_bounds__(256, 2) void out_gemm(
    const bf16_t* __restrict__ Oc, const bf16_t* __restrict__ Wo,
    const float* __restrict__ bo, float* __restrict__ Cout) {

    __shared__ __align__(16) bf16_t As[128 * LDSW];
    __shared__ __align__(16) bf16_t Bs[128 * LDSW];
    f32x4 acc[4][4];
    const int m0 = blockIdx.y * 128, n0 = blockIdx.x * 128;

    gemm_core(Oc, Wo, D_MODEL, m0, n0, As, Bs, acc);

    const int tid = threadIdx.x, lane = tid & 63, wid = tid >> 6;
    const int wm = (wid >> 1) * 64, wn = (wid & 1) * 64;
    const int l15 = lane & 15, quad = lane >> 4;

    #pragma unroll
    for (int i = 0; i < 4; i++)
        #pragma unroll
        for (int j = 0; j < 4; j++)
            #pragma unroll
            for (int r = 0; r < 4; r++) {
                int gm = m0 + wm + i * 16 + quad * 4 + r;
                int gn = n0 + wn + j * 16 + l15;
                Cout[(size_t)gm * D_MODEL + gn] = acc[i][j][r] + bo[gn];
            }
}

// ---- flash attention: one block = one (b,h) x 64-query tile; 64-key tiles ----
// R12 = R11 schedule (single-buffered K/V, phase-split staging, 24576B LDS ->
// 4 blocks/CU) with the R11 race CLOSED. R11's bug: drains waited vmcnt only;
// raw s_barrier doesn't drain lgkmcnt, and the compiler may sink the
// register-only MFMAs (with their lgkmcnt waits) below the barrier (rule:
// inline-asm waitcnt doesn't order register-only MFMA). A wave could pass the
// barrier with ds_reads of Ks/Vts still in flight while the next DMA
// overwrote the tile -> absmax 2e-2. Fix: drains are vmcnt(0)+lgkmcnt(0)
// (this wave's LDS reads COMPLETE before the barrier) + sched_barrier(0)
// after each s_barrier pins any stray ops above the DMA issues.
//   QK(kt) reads Ks  -> drain(V(kt) dma + my ds_reads), B1 -> issue K(kt+1)
//   softmax; PV(kt) reads Vts -> drain(K(kt+1) dma + ds_reads), B2 -> issue V(kt+1)
// Every DMA drain still has a full compute phase of slack (vs R9's zero).
__global__ __launch_bounds__(256) void attn_kernel(
    const bf16_t* __restrict__ Qh, const bf16_t* __restrict__ Kh,
    const bf16_t* __restrict__ Vt, bf16_t* __restrict__ Oc) {

    __shared__ __align__(16) bf16_t Ks[64 * LDSW];    // K tile [key][dk], swizzled
    __shared__ __align__(16) bf16_t Vts[64 * LDSW];   // V^T tile [dk][key], swizzled
    __shared__ __align__(16) bf16_t Pls[64 * LDSW];   // P / O-epilogue, swizzled

    const int tid = threadIdx.x, lane = tid & 63, wid = tid >> 6;
    const int l15 = lane & 15, quad = lane >> 4;
    const int bh = blockIdx.x;                 // XCD-friendly
    const int q0 = blockIdx.y * 64;
    const bf16_t* Qbase = Qh + (size_t)bh * SEQ * DK;
    const bf16_t* Kbase = Kh + (size_t)bh * SEQ * DK;
    const bf16_t* Vbase = Vt + (size_t)bh * DK * SEQ;

    const int lrow = lane >> 3;                  // 0..7 row within 8-row group
    const int gcol = ((lane & 7) ^ lrow) * 8;    // swizzled logical col (elems)

    // Q fragments: wave wid owns query rows [q0+wid*16, +16)
    bf16x8 aQ[2];
    #pragma unroll
    for (int c = 0; c < 2; c++)
        aQ[c] = ldfrag(Qbase + (size_t)(q0 + wid * 16 + l15) * DK + c * 32 + quad * 8);

    f32x4 oacc[4];
    #pragma unroll
    for (int j = 0; j < 4; j++) oacc[j] = zero4();
    float l_i[4] = {0.f, 0.f, 0.f, 0.f};

    // prologue: stage K(0), V(0) (4 DMA insts per wave); __syncthreads drains
    #pragma unroll
    for (int t = 0; t < 2; t++) {
        const int rbase = wid * 16 + t * 8;
        gll16(Kbase + (size_t)(rbase + lrow) * DK + gcol,  Ks  + rbase * LDSW);
        gll16(Vbase + (size_t)(rbase + lrow) * SEQ + gcol, Vts + rbase * LDSW);
    }
    __syncthreads();

    const int pch = l15 >> 3, pwi = l15 & 7;     // P-write chunk/within-chunk
    const int NT = SEQ / 64;

    for (int kt = 0; kt < NT; kt++) {
        // ---- S = Q*K^T over K(kt) (Q pre-scaled by log2e/8) ----
        f32x4 sacc[4];
        #pragma unroll
        for (int j = 0; j < 4; j++) sacc[j] = zero4();
        #pragma unroll
        for (int c = 0; c < 2; c++) {
            bf16x8 bk4[4];
            #pragma unroll
            for (int j = 0; j < 4; j++) {
                const int pc = ((c * 4 + quad) ^ (l15 & 7)) * 8;
                bk4[j] = ldfrag(Ks + (j * 16 + l15) * LDSW + pc);
            }
            #pragma unroll
            for (int j = 0; j < 4; j++)
                sacc[j] = __builtin_amdgcn_mfma_f32_16x16x32_bf16(
                    aQ[c], bk4[j], sacc[j], 0, 0, 0);
        }

        // drain V(kt)'s DMAs (full QK phase of slack) AND this wave's LDS
        // reads of Ks (lgkmcnt) so the upcoming K DMA can't clobber them.
        asm volatile("s_waitcnt vmcnt(0) lgkmcnt(0)" ::: "memory");
        __builtin_amdgcn_s_barrier();
        __builtin_amdgcn_sched_barrier(0);

        // issue K(kt+1) into Ks (all waves certified done with Ks at B1)
        if (kt + 1 < NT) {
            const int nk0 = (kt + 1) * 64;
            #pragma unroll
            for (int t = 0; t < 2; t++) {
                const int rbase = wid * 16 + t * 8;
                gll16(Kbase + (size_t)(nk0 + rbase + lrow) * DK + gcol, Ks + rbase * LDSW);
            }
        }

        // exp2, partial row sums, P -> wave-private LDS rows (swizzled chunks)
        #pragma unroll
        for (int r = 0; r < 4; r++) {
            float e0 = exp2f(sacc[0][r]);
            float e1 = exp2f(sacc[1][r]);
            float e2 = exp2f(sacc[2][r]);
            float e3 = exp2f(sacc[3][r]);
            l_i[r] += (e0 + e1) + (e2 + e3);
            bf16_t* prow = Pls + (wid * 16 + quad * 4 + r) * LDSW;
            const int rx = (quad * 4 + r) & 7;
            prow[((pch    ) ^ rx) * 8 + pwi] = (bf16_t)e0;
            prow[((pch + 2) ^ rx) * 8 + pwi] = (bf16_t)e1;
            prow[((pch + 4) ^ rx) * 8 + pwi] = (bf16_t)e2;
            prow[((pch + 6) ^ rx) * 8 + pwi] = (bf16_t)e3;
        }

        // ---- O += P*V over V(kt) (same-wave P write->read; lgkm handled) ----
        #pragma unroll
        for (int c = 0; c < 2; c++) {
            bf16x8 ap = ldfrag(Pls + (wid * 16 + l15) * LDSW +
                               (((c * 4 + quad) ^ (l15 & 7)) << 3));
            bf16x8 bv4[4];
            #pragma unroll
            for (int j = 0; j < 4; j++) {
                const int pc = ((c * 4 + quad) ^ (l15 & 7)) * 8;
                bv4[j] = ldfrag(Vts + (j * 16 + l15) * LDSW + pc);
            }
            #pragma unroll
            for (int j = 0; j < 4; j++)
                oacc[j] = __builtin_amdgcn_mfma_f32_16x16x32_bf16(
                    ap, bv4[j], oacc[j], 0, 0, 0);
        }

        // drain K(kt+1)'s DMAs (full softmax+PV slack) AND this wave's LDS
        // reads of Vts/Pls; B2 certifies all waves done with Vts.
        asm volatile("s_waitcnt vmcnt(0) lgkmcnt(0)" ::: "memory");
        __builtin_amdgcn_s_barrier();
        __builtin_amdgcn_sched_barrier(0);

        // issue V(kt+1) into Vts
        if (kt + 1 < NT) {
            const int nk0 = (kt + 1) * 64;
            #pragma unroll
            for (int t = 0; t < 2; t++) {
                const int rbase = wid * 16 + t * 8;
                gll16(Vbase + (size_t)(rbase + lrow) * SEQ + nk0 + gcol, Vts + rbase * LDSW);
            }
        }
    }

    // normalize, stage into Pls (swizzled), then coalesced 16B stores
    #pragma unroll
    for (int r = 0; r < 4; r++) {
        float l = l_i[r];
        #pragma unroll
        for (int off = 1; off < 16; off <<= 1)
            l += __shfl_xor(l, off, 64);
        float inv = 1.0f / l;
        bf16_t* prow = Pls + (wid * 16 + quad * 4 + r) * LDSW;
        const int rx = (quad * 4 + r) & 7;
        #pragma unroll
        for (int j = 0; j < 4; j++)
            prow[((pch + 2 * j) ^ rx) * 8 + pwi] = (bf16_t)(oacc[j][r] * inv);
    }
    __syncthreads();

    const int b = bh >> 4, h = bh & 15;
    #pragma unroll
    for (int c = tid; c < 512; c += 256) {   // 64 rows x 8 chunks of 8 bf16
        int row = c >> 3, chunk = c & 7;
        uint4 val = *reinterpret_cast<const uint4*>(
            Pls + row * LDSW + ((chunk ^ (row & 7)) << 3));
        *reinterpret_cast<uint4*>(Oc + ((size_t)(b * SEQ + q0 + row)) * D_MODEL + h * DK + (chunk << 3)) = val;
    }
}

extern "C" void kernel_launch(void* const* d_in, const int* in_sizes, int n_in,
                              void* d_out, int out_size, void* d_ws, size_t ws_size,
                              hipStream_t stream) {
    const float* q  = (const float*)d_in[0];
    const float* k  = (const float*)d_in[1];
    const float* v  = (const float*)d_in[2];
    const float* Wq = (const float*)d_in[3];
    const float* bq = (const float*)d_in[4];
    const float* Wk = (const float*)d_in[5];
    const float* bk = (const float*)d_in[6];
    const float* Wv = (const float*)d_in[7];
    const float* bv = (const float*)d_in[8];
    const float* Wo = (const float*)d_in[9];
    const float* bo = (const float*)d_in[10];

    const size_t nx = (size_t)MROWS * D_MODEL;   // 4,194,304
    const size_t nw = (size_t)D_MODEL * D_MODEL; // 1,048,576

    bf16_t* qb  = (bf16_t*)d_ws;
    bf16_t* kb  = qb  + nx;
    bf16_t* vb  = kb  + nx;
    bf16_t* Wqb = vb  + nx;
    bf16_t* Wkb = Wqb + nw;
    bf16_t* Wvb = Wkb + nw;
    bf16_t* Wob = Wvb + nw;
    bf16_t* Qh  = Wob + nw;   // [BH][S][DK]
    bf16_t* Kh  = Qh  + nx;   // [BH][S][DK]
    bf16_t* Vt  = Kh  + nx;   // [BH][DK][S]
    bf16_t* Oc  = Vt  + nx;   // [B*S][D]

    pack3<<<dim3(4096, 3), 256, 0, stream>>>(q, k, v, qb, kb, vb);
    pack4<<<dim3(1024, 4), 256, 0, stream>>>(Wq, Wk, Wv, Wo, Wqb, Wkb, Wvb, Wob);

    proj_gemm<<<dim3(8, 32, 3), 256, 0, stream>>>(qb, kb, vb, Wqb, Wkb, Wvb, bq, bk, bv, Qh, Kh, Vt);
    attn_kernel<<<dim3(32, 32), 256, 0, stream>>>(Qh, Kh, Vt, Oc);
    out_gemm<<<dim3(8, 32), 256, 0, stream>>>(Oc, Wob, bo, (float*)d_out);
}

// Round 4
// 242.793 us; speedup vs baseline: 1.0772x; 1.0639x over previous
//
#include <hip/hip_runtime.h>
#include <hip/hip_bf16.h>
#include <math.h>

// ---- types ----
typedef __bf16 bf16_t;
typedef bf16_t bf16x8 __attribute__((ext_vector_type(8)));
typedef float f32x4 __attribute__((ext_vector_type(4)));

#define D_MODEL 1024
#define NH 16
#define DK 64
#define SEQ 2048
#define MROWS 4096   // B*S
#define LDSW 64      // UNPADDED row width for async-DMA tiles (XOR-swizzled)
#define LDC 136      // padded row for the 128x128 epilogue staging tile

__device__ __forceinline__ bf16x8 ldfrag(const bf16_t* p) {
    union { uint4 u; bf16x8 v; } c;
    c.u = *reinterpret_cast<const uint4*>(p);
    return c.v;
}

__device__ __forceinline__ f32x4 zero4() { f32x4 z = {0.f, 0.f, 0.f, 0.f}; return z; }

// async global->LDS DMA, 16B per lane. LDS dest = wave-uniform base + lane*16.
__device__ __forceinline__ void gll16(const bf16_t* g, bf16_t* l) {
    __builtin_amdgcn_global_load_lds(
        (const __attribute__((address_space(1))) unsigned int*)g,
        (__attribute__((address_space(3))) unsigned int*)l,
        16, 0, 0);
}

// ---- fp32 -> bf16 pack, 3 tensors via blockIdx.y ----
__global__ void pack3(const float* __restrict__ a, const float* __restrict__ b,
                      const float* __restrict__ c,
                      bf16_t* __restrict__ da, bf16_t* __restrict__ db, bf16_t* __restrict__ dc) {
    const float* s = (blockIdx.y == 0) ? a : (blockIdx.y == 1) ? b : c;
    bf16_t* d      = (blockIdx.y == 0) ? da : (blockIdx.y == 1) ? db : dc;
    int i = (blockIdx.x * blockDim.x + threadIdx.x) * 4;
    float4 f = *reinterpret_cast<const float4*>(s + i);
    union { bf16_t h[4]; uint2 u; } o;
    o.h[0] = (bf16_t)f.x; o.h[1] = (bf16_t)f.y; o.h[2] = (bf16_t)f.z; o.h[3] = (bf16_t)f.w;
    *reinterpret_cast<uint2*>(d + i) = o.u;
}

// ---- fp32 -> bf16 pack, 4 weight matrices via blockIdx.y ----
__global__ void pack4(const float* __restrict__ a, const float* __restrict__ b,
                      const float* __restrict__ c, const float* __restrict__ e,
                      bf16_t* __restrict__ da, bf16_t* __restrict__ db,
                      bf16_t* __restrict__ dc, bf16_t* __restrict__ de) {
    const float* s = (blockIdx.y == 0) ? a : (blockIdx.y == 1) ? b : (blockIdx.y == 2) ? c : e;
    bf16_t* d      = (blockIdx.y == 0) ? da : (blockIdx.y == 1) ? db : (blockIdx.y == 2) ? dc : de;
    int i = (blockIdx.x * blockDim.x + threadIdx.x) * 4;
    float4 f = *reinterpret_cast<const float4*>(s + i);
    union { bf16_t h[4]; uint2 u; } o;
    o.h[0] = (bf16_t)f.x; o.h[1] = (bf16_t)f.y; o.h[2] = (bf16_t)f.z; o.h[3] = (bf16_t)f.w;
    *reinterpret_cast<uint2*>(d + i) = o.u;
}

// ---- shared GEMM core: C(128x128) = A(rowmaj MxK) * B(rowmaj NxK)^T ----
// m97 structure: async global_load_lds staging; unpadded [128][64] tiles with
// XOR 16B-chunk swizzle (phys chunk p of row r holds logical chunk p^(r&7)).
__device__ __forceinline__ void gemm_core(
    const bf16_t* __restrict__ A, const bf16_t* __restrict__ Bm,
    int K, int m0, int n0,
    bf16_t* As, bf16_t* Bs,       // each 128*LDSW bf16
    f32x4 acc[4][4]) {

    const int tid = threadIdx.x;
    const int lane = tid & 63;
    const int wid = tid >> 6;
    const int wm = (wid >> 1) * 64, wn = (wid & 1) * 64;
    const int l15 = lane & 15, quad = lane >> 4;

    const int lrow   = lane >> 3;                // 0..7 row within 8-row group
    const int gcol   = ((lane & 7) ^ lrow) * 8;  // swizzled logical col (elems)

    #pragma unroll
    for (int i = 0; i < 4; i++)
        #pragma unroll
        for (int j = 0; j < 4; j++) acc[i][j] = zero4();

    for (int k0 = 0; k0 < K; k0 += 64) {
        __syncthreads();
        #pragma unroll
        for (int t = 0; t < 4; t++) {
            const int rbase = wid * 32 + t * 8;
            gll16(A  + (size_t)(m0 + rbase + lrow) * K + k0 + gcol, As + rbase * LDSW);
            gll16(Bm + (size_t)(n0 + rbase + lrow) * K + k0 + gcol, Bs + rbase * LDSW);
        }
        __syncthreads();
        #pragma unroll
        for (int c = 0; c < 2; c++) {
            bf16x8 af[4], bfr[4];
            #pragma unroll
            for (int i = 0; i < 4; i++) {
                const int row = wm + i * 16 + l15;
                const int pc = ((c * 4 + quad) ^ (l15 & 7)) * 8;
                af[i] = ldfrag(As + row * LDSW + pc);
            }
            #pragma unroll
            for (int j = 0; j < 4; j++) {
                const int row = wn + j * 16 + l15;
                const int pc = ((c * 4 + quad) ^ (l15 & 7)) * 8;
                bfr[j] = ldfrag(Bs + row * LDSW + pc);
            }
            #pragma unroll
            for (int i = 0; i < 4; i++)
                #pragma unroll
                for (int j = 0; j < 4; j++)
                    acc[i][j] = __builtin_amdgcn_mfma_f32_16x16x32_bf16(af[i], bfr[j], acc[i][j], 0, 0, 0);
        }
    }
}

// ---- fused Q/K/V projection: blockIdx.z picks which ----
__global__ __launch_bounds__(256, 2) void proj_gemm(
    const bf16_t* __restrict__ qb, const bf16_t* __restrict__ kb,
    const bf16_t* __restrict__ vb,
    const bf16_t* __restrict__ Wq, const bf16_t* __restrict__ Wk,
    const bf16_t* __restrict__ Wv,
    const float* __restrict__ bq, const float* __restrict__ bk, const float* __restrict__ bv,
    bf16_t* __restrict__ Qh, bf16_t* __restrict__ Kh, bf16_t* __restrict__ Vt) {

    __shared__ __align__(16) bf16_t sm[128 * LDC];   // 34816B: As|Bs, reused as Cs
    bf16_t* As = sm;
    bf16_t* Bs = sm + 128 * LDSW;
    bf16_t (*Cs)[LDC] = reinterpret_cast<bf16_t(*)[LDC]>(sm);
    f32x4 acc[4][4];

    const int mode = blockIdx.z;
    const bf16_t* X = (mode == 0) ? qb : (mode == 1) ? kb : vb;
    const bf16_t* W = (mode == 0) ? Wq : (mode == 1) ? Wk : Wv;
    const float* bias = (mode == 0) ? bq : (mode == 1) ? bk : bv;
    const int m0 = blockIdx.y * 128, n0 = blockIdx.x * 128;

    gemm_core(X, W, D_MODEL, m0, n0, As, Bs, acc);

    const int tid = threadIdx.x, lane = tid & 63, wid = tid >> 6;
    const int wm = (wid >> 1) * 64, wn = (wid & 1) * 64;
    const int l15 = lane & 15, quad = lane >> 4;

    __syncthreads();
    if (mode != 2) {
        // Q gets 1/sqrt(dk) * log2(e) folded in so attn can use raw exp2
        const float sc = (mode == 0) ? 0.125f * 1.44269504f : 1.0f;
        #pragma unroll
        for (int i = 0; i < 4; i++)
            #pragma unroll
            for (int j = 0; j < 4; j++)
                #pragma unroll
                for (int r = 0; r < 4; r++) {
                    int gn = n0 + wn + j * 16 + l15;
                    Cs[wm + i * 16 + quad * 4 + r][wn + j * 16 + l15] =
                        (bf16_t)((acc[i][j][r] + bias[gn]) * sc);
                }
    } else {
        #pragma unroll
        for (int i = 0; i < 4; i++)
            #pragma unroll
            for (int j = 0; j < 4; j++)
                #pragma unroll
                for (int r = 0; r < 4; r++) {
                    int gn = n0 + wn + j * 16 + l15;
                    Cs[wn + j * 16 + l15][wm + i * 16 + quad * 4 + r] =
                        (bf16_t)(acc[i][j][r] + bias[gn]);
                }
    }
    __syncthreads();

    #pragma unroll
    for (int c = tid; c < 2048; c += 256) {
        int row = c >> 4, col8 = (c & 15) << 3;
        uint4 val = *reinterpret_cast<const uint4*>(&Cs[row][col8]);
        if (mode != 2) {
            int gm = m0 + row, gn = n0 + col8;
            int b = gm >> 11, seq = gm & 2047;
            int h = gn >> 6, dk = gn & 63;
            bf16_t* dst = (mode == 0) ? Qh : Kh;
            *reinterpret_cast<uint4*>(dst + ((size_t)(b * NH + h) * SEQ + seq) * DK + dk) = val;
        } else {
            int gn = n0 + row, gm = m0 + col8;
            int b = gm >> 11, seq = gm & 2047;
            int h = gn >> 6, dk = gn & 63;
            *reinterpret_cast<uint4*>(Vt + ((size_t)(b * NH + h) * DK + dk) * SEQ + seq) = val;
        }
    }
}

// ---- output projection: fp32 out + bias ----
__global__ __launch_bounds__(256, 2) void out_gemm(
    const bf16_t* __restrict__ Oc, const bf16_t* __restrict__ Wo,
    const float* __restrict__ bo, float* __restrict__ Cout) {

    __shared__ __align__(16) bf16_t As[128 * LDSW];
    __shared__ __align__(16) bf16_t Bs[128 * LDSW];
    f32x4 acc[4][4];
    const int m0 = blockIdx.y * 128, n0 = blockIdx.x * 128;

    gemm_core(Oc, Wo, D_MODEL, m0, n0, As, Bs, acc);

    const int tid = threadIdx.x, lane = tid & 63, wid = tid >> 6;
    const int wm = (wid >> 1) * 64, wn = (wid & 1) * 64;
    const int l15 = lane & 15, quad = lane >> 4;

    #pragma unroll
    for (int i = 0; i < 4; i++)
        #pragma unroll
        for (int j = 0; j < 4; j++)
            #pragma unroll
            for (int r = 0; r < 4; r++) {
                int gm = m0 + wm + i * 16 + quad * 4 + r;
                int gn = n0 + wn + j * 16 + l15;
                Cout[(size_t)gm * D_MODEL + gn] = acc[i][j][r] + bo[gn];
            }
}

// ---- flash attention: one block = one (b,h) x 64-query tile; 64-key tiles ----
// R13 = R9's proven loop schedule (stage -> __syncthreads drain -> compute;
// TLP across 4 blocks/CU hides the drain — R10/R12 pipelining attempts both
// measured SLOWER) + swapped-QK^T softmax to cut VALU/LDS work:
//   sacc[j] = mfma(K_frag, Q_frag)  ->  S^T[key][q]: lane(l15,quad) holds,
//   per j, keys j*16+quad*4+{0..3} for its OWN q=l15. The 4 values pack into
//   one u64 (compiler fuses v_cvt_pk_bf16_f32) -> 4 ds_write_b64 replaces
//   16 ds_write_b16 + 16 addr computations. P row-major [q][key] with the
//   R12 XOR-chunk swizzle (0 bank conflicts); PV A-fragment read unchanged.
//   l_i collapses to one scalar/lane (reduce = 2 shfl_xor over quad bits).
// LDS 24576B -> 4 blocks/CU. No inline-asm scheduling in the loop.
__global__ __launch_bounds__(256) void attn_kernel(
    const bf16_t* __restrict__ Qh, const bf16_t* __restrict__ Kh,
    const bf16_t* __restrict__ Vt, bf16_t* __restrict__ Oc) {

    __shared__ __align__(16) bf16_t Ks[64 * LDSW];    // K tile [key][dk], swizzled
    __shared__ __align__(16) bf16_t Vts[64 * LDSW];   // V^T tile [dk][key], swizzled
    __shared__ __align__(16) bf16_t Pls[64 * LDSW];   // P / O-epilogue, swizzled

    const int tid = threadIdx.x, lane = tid & 63, wid = tid >> 6;
    const int l15 = lane & 15, quad = lane >> 4;
    const int bh = blockIdx.x;                 // XCD-friendly
    const int q0 = blockIdx.y * 64;
    const bf16_t* Qbase = Qh + (size_t)bh * SEQ * DK;
    const bf16_t* Kbase = Kh + (size_t)bh * SEQ * DK;
    const bf16_t* Vbase = Vt + (size_t)bh * DK * SEQ;

    const int lrow = lane >> 3;                  // 0..7 row within 8-row group
    const int gcol = ((lane & 7) ^ lrow) * 8;    // swizzled logical col (elems)

    // Q fragments: wave wid owns query rows [q0+wid*16, +16)
    bf16x8 aQ[2];
    #pragma unroll
    for (int c = 0; c < 2; c++)
        aQ[c] = ldfrag(Qbase + (size_t)(q0 + wid * 16 + l15) * DK + c * 32 + quad * 8);

    f32x4 oacc[4];
    #pragma unroll
    for (int j = 0; j < 4; j++) oacc[j] = zero4();
    float l_acc = 0.f;

    const int s7 = l15 & 7;
    bf16_t* prow = Pls + (wid * 16 + l15) * LDSW;   // this lane's P row (q=l15)

    for (int kt = 0; kt < SEQ / 64; kt++) {
        const int k0 = kt * 64;
        __syncthreads();   // prev-iter reads of Ks/Vts done
        // wave wid stages rows [wid*16, wid*16+16) of both tiles (2+2 DMA insts)
        #pragma unroll
        for (int t = 0; t < 2; t++) {
            const int rbase = wid * 16 + t * 8;
            gll16(Kbase + (size_t)(k0 + rbase + lrow) * DK + gcol,  Ks  + rbase * LDSW);
            gll16(Vbase + (size_t)(rbase + lrow) * SEQ + k0 + gcol, Vts + rbase * LDSW);
        }
        __syncthreads();   // barrier drains vmcnt -> DMA complete

        // S^T = K*Q^T (Q pre-scaled by log2e/8).  A=K_frag, B=Q_frag — both
        // fragments have the identical lane layout, so the swap is free.
        // sacc[j][r] = S[key = j*16+quad*4+r][q = q0+wid*16+l15]
        f32x4 sacc[4];
        #pragma unroll
        for (int j = 0; j < 4; j++) sacc[j] = zero4();
        #pragma unroll
        for (int c = 0; c < 2; c++) {
            bf16x8 bk4[4];
            #pragma unroll
            for (int j = 0; j < 4; j++) {
                const int pc = ((c * 4 + quad) ^ s7) * 8;
                bk4[j] = ldfrag(Ks + (j * 16 + l15) * LDSW + pc);
            }
            #pragma unroll
            for (int j = 0; j < 4; j++)
                sacc[j] = __builtin_amdgcn_mfma_f32_16x16x32_bf16(
                    bk4[j], aQ[c], sacc[j], 0, 0, 0);
        }

        // exp2 + scalar row-sum + PACKED P write: per j, keys j*16+quad*4+..+3
        // are consecutive -> one u64 (2 fused cvt_pk) per j, 4 writes total.
        #pragma unroll
        for (int j = 0; j < 4; j++) {
            float e0 = exp2f(sacc[j][0]);
            float e1 = exp2f(sacc[j][1]);
            float e2 = exp2f(sacc[j][2]);
            float e3 = exp2f(sacc[j][3]);
            l_acc += (e0 + e1) + (e2 + e3);
            union { bf16_t h[4]; unsigned long long u; } pk;
            pk.h[0] = (bf16_t)e0; pk.h[1] = (bf16_t)e1;
            pk.h[2] = (bf16_t)e2; pk.h[3] = (bf16_t)e3;
            const int Lc = j * 2 + (quad >> 1);          // logical 16B chunk
            *reinterpret_cast<unsigned long long*>(
                prow + ((Lc ^ s7) << 3) + ((quad & 1) << 2)) = pk.u;
        }

        // O += P*V (same-wave LDS write->read; compiler inserts lgkmcnt wait)
        #pragma unroll
        for (int c = 0; c < 2; c++) {
            bf16x8 ap = ldfrag(prow + (((c * 4 + quad) ^ s7) << 3));
            bf16x8 bv4[4];
            #pragma unroll
            for (int j = 0; j < 4; j++) {
                const int pc = ((c * 4 + quad) ^ s7) * 8;
                bv4[j] = ldfrag(Vts + (j * 16 + l15) * LDSW + pc);
            }
            #pragma unroll
            for (int j = 0; j < 4; j++)
                oacc[j] = __builtin_amdgcn_mfma_f32_16x16x32_bf16(
                    ap, bv4[j], oacc[j], 0, 0, 0);
        }
    }

    // normalize: l_acc holds partial sum for q=l15 over this quad's keys;
    // reduce over the 4 quads (lanes l15, l15+16, l15+32, l15+48)
    float l = l_acc;
    l += __shfl_xor(l, 16, 64);
    l += __shfl_xor(l, 32, 64);

    const int pch = l15 >> 3, pwi = l15 & 7;
    #pragma unroll
    for (int r = 0; r < 4; r++) {
        // O row q = wid*16+quad*4+r; its row-sum lives at lane l15==quad*4+r
        float lr = __shfl(l, quad * 4 + r, 16);
        float inv = 1.0f / lr;
        bf16_t* orow = Pls + (wid * 16 + quad * 4 + r) * LDSW;
        const int rx = (quad * 4 + r) & 7;
        #pragma unroll
        for (int j = 0; j < 4; j++)
            orow[((pch + 2 * j) ^ rx) * 8 + pwi] = (bf16_t)(oacc[j][r] * inv);
    }
    __syncthreads();

    const int b = bh >> 4, h = bh & 15;
    #pragma unroll
    for (int c = tid; c < 512; c += 256) {   // 64 rows x 8 chunks of 8 bf16
        int row = c >> 3, chunk = c & 7;
        uint4 val = *reinterpret_cast<const uint4*>(
            Pls + row * LDSW + ((chunk ^ (row & 7)) << 3));
        *reinterpret_cast<uint4*>(Oc + ((size_t)(b * SEQ + q0 + row)) * D_MODEL + h * DK + (chunk << 3)) = val;
    }
}

extern "C" void kernel_launch(void* const* d_in, const int* in_sizes, int n_in,
                              void* d_out, int out_size, void* d_ws, size_t ws_size,
                              hipStream_t stream) {
    const float* q  = (const float*)d_in[0];
    const float* k  = (const float*)d_in[1];
    const float* v  = (const float*)d_in[2];
    const float* Wq = (const float*)d_in[3];
    const float* bq = (const float*)d_in[4];
    const float* Wk = (const float*)d_in[5];
    const float* bk = (const float*)d_in[6];
    const float* Wv = (const float*)d_in[7];
    const float* bv = (const float*)d_in[8];
    const float* Wo = (const float*)d_in[9];
    const float* bo = (const float*)d_in[10];

    const size_t nx = (size_t)MROWS * D_MODEL;   // 4,194,304
    const size_t nw = (size_t)D_MODEL * D_MODEL; // 1,048,576

    bf16_t* qb  = (bf16_t*)d_ws;
    bf16_t* kb  = qb  + nx;
    bf16_t* vb  = kb  + nx;
    bf16_t* Wqb = vb  + nx;
    bf16_t* Wkb = Wqb + nw;
    bf16_t* Wvb = Wkb + nw;
    bf16_t* Wob = Wvb + nw;
    bf16_t* Qh  = Wob + nw;   // [BH][S][DK]
    bf16_t* Kh  = Qh  + nx;   // [BH][S][DK]
    bf16_t* Vt  = Kh  + nx;   // [BH][DK][S]
    bf16_t* Oc  = Vt  + nx;   // [B*S][D]

    pack3<<<dim3(4096, 3), 256, 0, stream>>>(q, k, v, qb, kb, vb);
    pack4<<<dim3(1024, 4), 256, 0, stream>>>(Wq, Wk, Wv, Wo, Wqb, Wkb, Wvb, Wob);

    proj_gemm<<<dim3(8, 32, 3), 256, 0, stream>>>(qb, kb, vb, Wqb, Wkb, Wvb, bq, bk, bv, Qh, Kh, Vt);
    attn_kernel<<<dim3(32, 32), 256, 0, stream>>>(Qh, Kh, Vt, Oc);
    out_gemm<<<dim3(8, 32), 256, 0, stream>>>(Oc, Wob, bo, (float*)d_out);
}

// Round 5
// 239.571 us; speedup vs baseline: 1.0916x; 1.0134x over previous
//
#include <hip/hip_runtime.h>
#include <hip/hip_bf16.h>
#include <math.h>

// ---- types ----
typedef __bf16 bf16_t;
typedef bf16_t bf16x8 __attribute__((ext_vector_type(8)));
typedef float f32x4 __attribute__((ext_vector_type(4)));

#define D_MODEL 1024
#define NH 16
#define DK 64
#define SEQ 2048
#define MROWS 4096   // B*S
#define LDSW 64      // UNPADDED row width for async-DMA tiles (XOR-swizzled)
#define LDC 136      // padded row for the 128x128 epilogue staging tile

__device__ __forceinline__ bf16x8 ldfrag(const bf16_t* p) {
    union { uint4 u; bf16x8 v; } c;
    c.u = *reinterpret_cast<const uint4*>(p);
    return c.v;
}

__device__ __forceinline__ f32x4 zero4() { f32x4 z = {0.f, 0.f, 0.f, 0.f}; return z; }

// async global->LDS DMA, 16B per lane. LDS dest = wave-uniform base + lane*16.
__device__ __forceinline__ void gll16(const bf16_t* g, bf16_t* l) {
    __builtin_amdgcn_global_load_lds(
        (const __attribute__((address_space(1))) unsigned int*)g,
        (__attribute__((address_space(3))) unsigned int*)l,
        16, 0, 0);
}

// ---- fp32 -> bf16 pack, all 7 tensors in one launch ----
// y<3: q/k/v (4096 blocks each); y>=3: the 4 weight matrices (1024 blocks,
// guarded). Saves one kernel launch vs separate pack3/pack4.
__global__ void pack7(const float* __restrict__ q, const float* __restrict__ k,
                      const float* __restrict__ v, const float* __restrict__ wq,
                      const float* __restrict__ wk, const float* __restrict__ wv,
                      const float* __restrict__ wo,
                      bf16_t* __restrict__ dq, bf16_t* __restrict__ dk,
                      bf16_t* __restrict__ dv, bf16_t* __restrict__ dwq,
                      bf16_t* __restrict__ dwk, bf16_t* __restrict__ dwv,
                      bf16_t* __restrict__ dwo) {
    const int y = blockIdx.y;
    if (y >= 3 && blockIdx.x >= 1024) return;   // weights are 1/4 the size
    const float* s;
    bf16_t* d;
    switch (y) {
        case 0: s = q;  d = dq;  break;
        case 1: s = k;  d = dk;  break;
        case 2: s = v;  d = dv;  break;
        case 3: s = wq; d = dwq; break;
        case 4: s = wk; d = dwk; break;
        case 5: s = wv; d = dwv; break;
        default: s = wo; d = dwo; break;
    }
    int i = (blockIdx.x * blockDim.x + threadIdx.x) * 4;
    float4 f = *reinterpret_cast<const float4*>(s + i);
    union { bf16_t h[4]; uint2 u; } o;
    o.h[0] = (bf16_t)f.x; o.h[1] = (bf16_t)f.y; o.h[2] = (bf16_t)f.z; o.h[3] = (bf16_t)f.w;
    *reinterpret_cast<uint2*>(d + i) = o.u;
}

// ---- shared GEMM core: C(128x128) = A(rowmaj MxK) * B(rowmaj NxK)^T ----
// m97 structure: async global_load_lds staging; unpadded [128][64] tiles with
// XOR 16B-chunk swizzle (phys chunk p of row r holds logical chunk p^(r&7)).
__device__ __forceinline__ void gemm_core(
    const bf16_t* __restrict__ A, const bf16_t* __restrict__ Bm,
    int K, int m0, int n0,
    bf16_t* As, bf16_t* Bs,       // each 128*LDSW bf16
    f32x4 acc[4][4]) {

    const int tid = threadIdx.x;
    const int lane = tid & 63;
    const int wid = tid >> 6;
    const int wm = (wid >> 1) * 64, wn = (wid & 1) * 64;
    const int l15 = lane & 15, quad = lane >> 4;

    const int lrow   = lane >> 3;                // 0..7 row within 8-row group
    const int gcol   = ((lane & 7) ^ lrow) * 8;  // swizzled logical col (elems)

    #pragma unroll
    for (int i = 0; i < 4; i++)
        #pragma unroll
        for (int j = 0; j < 4; j++) acc[i][j] = zero4();

    for (int k0 = 0; k0 < K; k0 += 64) {
        __syncthreads();
        #pragma unroll
        for (int t = 0; t < 4; t++) {
            const int rbase = wid * 32 + t * 8;
            gll16(A  + (size_t)(m0 + rbase + lrow) * K + k0 + gcol, As + rbase * LDSW);
            gll16(Bm + (size_t)(n0 + rbase + lrow) * K + k0 + gcol, Bs + rbase * LDSW);
        }
        __syncthreads();
        #pragma unroll
        for (int c = 0; c < 2; c++) {
            bf16x8 af[4], bfr[4];
            #pragma unroll
            for (int i = 0; i < 4; i++) {
                const int row = wm + i * 16 + l15;
                const int pc = ((c * 4 + quad) ^ (l15 & 7)) * 8;
                af[i] = ldfrag(As + row * LDSW + pc);
            }
            #pragma unroll
            for (int j = 0; j < 4; j++) {
                const int row = wn + j * 16 + l15;
                const int pc = ((c * 4 + quad) ^ (l15 & 7)) * 8;
                bfr[j] = ldfrag(Bs + row * LDSW + pc);
            }
            #pragma unroll
            for (int i = 0; i < 4; i++)
                #pragma unroll
                for (int j = 0; j < 4; j++)
                    acc[i][j] = __builtin_amdgcn_mfma_f32_16x16x32_bf16(af[i], bfr[j], acc[i][j], 0, 0, 0);
        }
    }
}

// ---- fused Q/K/V projection: blockIdx.z picks which ----
// R14: launch_bounds (256,2) -> (256,3). Grid = 768 blocks = 3/CU wanted;
// the 2-block cap forced a full straggler round. LDS 34.8KB allows 4; VGPR
// (~130) fits the 3-wave/EU cap (<=170).
__global__ __launch_bounds__(256, 3) void proj_gemm(
    const bf16_t* __restrict__ qb, const bf16_t* __restrict__ kb,
    const bf16_t* __restrict__ vb,
    const bf16_t* __restrict__ Wq, const bf16_t* __restrict__ Wk,
    const bf16_t* __restrict__ Wv,
    const float* __restrict__ bq, const float* __restrict__ bk, const float* __restrict__ bv,
    bf16_t* __restrict__ Qh, bf16_t* __restrict__ Kh, bf16_t* __restrict__ Vt) {

    __shared__ __align__(16) bf16_t sm[128 * LDC];   // 34816B: As|Bs, reused as Cs
    bf16_t* As = sm;
    bf16_t* Bs = sm + 128 * LDSW;
    bf16_t (*Cs)[LDC] = reinterpret_cast<bf16_t(*)[LDC]>(sm);
    f32x4 acc[4][4];

    const int mode = blockIdx.z;
    const bf16_t* X = (mode == 0) ? qb : (mode == 1) ? kb : vb;
    const bf16_t* W = (mode == 0) ? Wq : (mode == 1) ? Wk : Wv;
    const float* bias = (mode == 0) ? bq : (mode == 1) ? bk : bv;
    const int m0 = blockIdx.y * 128, n0 = blockIdx.x * 128;

    gemm_core(X, W, D_MODEL, m0, n0, As, Bs, acc);

    const int tid = threadIdx.x, lane = tid & 63, wid = tid >> 6;
    const int wm = (wid >> 1) * 64, wn = (wid & 1) * 64;
    const int l15 = lane & 15, quad = lane >> 4;

    __syncthreads();
    if (mode != 2) {
        // Q gets 1/sqrt(dk) * log2(e) folded in so attn can use raw exp2
        const float sc = (mode == 0) ? 0.125f * 1.44269504f : 1.0f;
        #pragma unroll
        for (int i = 0; i < 4; i++)
            #pragma unroll
            for (int j = 0; j < 4; j++)
                #pragma unroll
                for (int r = 0; r < 4; r++) {
                    int gn = n0 + wn + j * 16 + l15;
                    Cs[wm + i * 16 + quad * 4 + r][wn + j * 16 + l15] =
                        (bf16_t)((acc[i][j][r] + bias[gn]) * sc);
                }
    } else {
        #pragma unroll
        for (int i = 0; i < 4; i++)
            #pragma unroll
            for (int j = 0; j < 4; j++)
                #pragma unroll
                for (int r = 0; r < 4; r++) {
                    int gn = n0 + wn + j * 16 + l15;
                    Cs[wn + j * 16 + l15][wm + i * 16 + quad * 4 + r] =
                        (bf16_t)(acc[i][j][r] + bias[gn]);
                }
    }
    __syncthreads();

    #pragma unroll
    for (int c = tid; c < 2048; c += 256) {
        int row = c >> 4, col8 = (c & 15) << 3;
        uint4 val = *reinterpret_cast<const uint4*>(&Cs[row][col8]);
        if (mode != 2) {
            int gm = m0 + row, gn = n0 + col8;
            int b = gm >> 11, seq = gm & 2047;
            int h = gn >> 6, dk = gn & 63;
            bf16_t* dst = (mode == 0) ? Qh : Kh;
            *reinterpret_cast<uint4*>(dst + ((size_t)(b * NH + h) * SEQ + seq) * DK + dk) = val;
        } else {
            int gn = n0 + row, gm = m0 + col8;
            int b = gm >> 11, seq = gm & 2047;
            int h = gn >> 6, dk = gn & 63;
            *reinterpret_cast<uint4*>(Vt + ((size_t)(b * NH + h) * DK + dk) * SEQ + seq) = val;
        }
    }
}

// ---- output projection: 64x128 tiles for TLP ----
// R14: old 128x128 grid was 256 blocks = 1 block/CU = 1 wave/SIMD -> no
// latency hiding. 64x128 tiles -> grid (8,64) = 512 blocks = 2 blocks/CU,
// 8 waves/CU. LDS 24576B. Per-wave tile 32x64: acc[2][4].
__global__ __launch_bounds__(256, 2) void out_gemm(
    const bf16_t* __restrict__ Oc, const bf16_t* __restrict__ Wo,
    const float* __restrict__ bo, float* __restrict__ Cout) {

    __shared__ __align__(16) bf16_t As[64 * LDSW];    // 64 M-rows
    __shared__ __align__(16) bf16_t Bs[128 * LDSW];   // 128 N-rows
    f32x4 acc[2][4];
    const int m0 = blockIdx.y * 64, n0 = blockIdx.x * 128;

    const int tid = threadIdx.x;
    const int lane = tid & 63;
    const int wid = tid >> 6;
    const int wm = (wid >> 1) * 32, wn = (wid & 1) * 64;
    const int l15 = lane & 15, quad = lane >> 4;
    const int lrow = lane >> 3;
    const int gcol = ((lane & 7) ^ lrow) * 8;

    #pragma unroll
    for (int i = 0; i < 2; i++)
        #pragma unroll
        for (int j = 0; j < 4; j++) acc[i][j] = zero4();

    for (int k0 = 0; k0 < D_MODEL; k0 += 64) {
        __syncthreads();
        // A: 64 rows -> 2 gll16/wave; B: 128 rows -> 4 gll16/wave
        #pragma unroll
        for (int t = 0; t < 2; t++) {
            const int rbase = wid * 16 + t * 8;
            gll16(Oc + (size_t)(m0 + rbase + lrow) * D_MODEL + k0 + gcol, As + rbase * LDSW);
        }
        #pragma unroll
        for (int t = 0; t < 4; t++) {
            const int rbase = wid * 32 + t * 8;
            gll16(Wo + (size_t)(n0 + rbase + lrow) * D_MODEL + k0 + gcol, Bs + rbase * LDSW);
        }
        __syncthreads();
        #pragma unroll
        for (int c = 0; c < 2; c++) {
            bf16x8 af[2], bfr[4];
            #pragma unroll
            for (int i = 0; i < 2; i++) {
                const int row = wm + i * 16 + l15;
                const int pc = ((c * 4 + quad) ^ (l15 & 7)) * 8;
                af[i] = ldfrag(As + row * LDSW + pc);
            }
            #pragma unroll
            for (int j = 0; j < 4; j++) {
                const int row = wn + j * 16 + l15;
                const int pc = ((c * 4 + quad) ^ (l15 & 7)) * 8;
                bfr[j] = ldfrag(Bs + row * LDSW + pc);
            }
            #pragma unroll
            for (int i = 0; i < 2; i++)
                #pragma unroll
                for (int j = 0; j < 4; j++)
                    acc[i][j] = __builtin_amdgcn_mfma_f32_16x16x32_bf16(af[i], bfr[j], acc[i][j], 0, 0, 0);
        }
    }

    #pragma unroll
    for (int i = 0; i < 2; i++)
        #pragma unroll
        for (int j = 0; j < 4; j++)
            #pragma unroll
            for (int r = 0; r < 4; r++) {
                int gm = m0 + wm + i * 16 + quad * 4 + r;
                int gn = n0 + wn + j * 16 + l15;
                Cout[(size_t)gm * D_MODEL + gn] = acc[i][j][r] + bo[gn];
            }
}

// ---- flash attention: one block = one (b,h) x 64-query tile; 64-key tiles ----
// R13 (verified 85.6 -> 77.9 µs): R9's loop schedule (stage -> __syncthreads
// drain -> compute; TLP across 4 blocks/CU hides the drain — R10/R12
// pipelining attempts both measured SLOWER) + swapped-QK^T softmax:
//   sacc[j] = mfma(K_frag, Q_frag)  ->  S^T[key][q]: lane(l15,quad) holds,
//   per j, keys j*16+quad*4+{0..3} for its OWN q=l15 -> packed u64 P-writes
//   (4 ds_write_b64 vs 16 ds_write_b16), scalar l_acc, 2-shfl reduce.
// Note: the ~2.1M bank-conflict cycles on the b64 writes are INHERENT to a
// 128B-row P layout (32 lanes -> 8 chunk slots = 4-way by pigeonhole, for
// any per-row chunk permutation); ~2-3 µs, partly hidden. Left as is.
__global__ __launch_bounds__(256) void attn_kernel(
    const bf16_t* __restrict__ Qh, const bf16_t* __restrict__ Kh,
    const bf16_t* __restrict__ Vt, bf16_t* __restrict__ Oc) {

    __shared__ __align__(16) bf16_t Ks[64 * LDSW];    // K tile [key][dk], swizzled
    __shared__ __align__(16) bf16_t Vts[64 * LDSW];   // V^T tile [dk][key], swizzled
    __shared__ __align__(16) bf16_t Pls[64 * LDSW];   // P / O-epilogue, swizzled

    const int tid = threadIdx.x, lane = tid & 63, wid = tid >> 6;
    const int l15 = lane & 15, quad = lane >> 4;
    const int bh = blockIdx.x;                 // XCD-friendly
    const int q0 = blockIdx.y * 64;
    const bf16_t* Qbase = Qh + (size_t)bh * SEQ * DK;
    const bf16_t* Kbase = Kh + (size_t)bh * SEQ * DK;
    const bf16_t* Vbase = Vt + (size_t)bh * DK * SEQ;

    const int lrow = lane >> 3;                  // 0..7 row within 8-row group
    const int gcol = ((lane & 7) ^ lrow) * 8;    // swizzled logical col (elems)

    // Q fragments: wave wid owns query rows [q0+wid*16, +16)
    bf16x8 aQ[2];
    #pragma unroll
    for (int c = 0; c < 2; c++)
        aQ[c] = ldfrag(Qbase + (size_t)(q0 + wid * 16 + l15) * DK + c * 32 + quad * 8);

    f32x4 oacc[4];
    #pragma unroll
    for (int j = 0; j < 4; j++) oacc[j] = zero4();
    float l_acc = 0.f;

    const int s7 = l15 & 7;
    bf16_t* prow = Pls + (wid * 16 + l15) * LDSW;   // this lane's P row (q=l15)

    for (int kt = 0; kt < SEQ / 64; kt++) {
        const int k0 = kt * 64;
        __syncthreads();   // prev-iter reads of Ks/Vts done
        // wave wid stages rows [wid*16, wid*16+16) of both tiles (2+2 DMA insts)
        #pragma unroll
        for (int t = 0; t < 2; t++) {
            const int rbase = wid * 16 + t * 8;
            gll16(Kbase + (size_t)(k0 + rbase + lrow) * DK + gcol,  Ks  + rbase * LDSW);
            gll16(Vbase + (size_t)(rbase + lrow) * SEQ + k0 + gcol, Vts + rbase * LDSW);
        }
        __syncthreads();   // barrier drains vmcnt -> DMA complete

        // S^T = K*Q^T (Q pre-scaled by log2e/8).  A=K_frag, B=Q_frag — both
        // fragments have the identical lane layout, so the swap is free.
        // sacc[j][r] = S[key = j*16+quad*4+r][q = q0+wid*16+l15]
        f32x4 sacc[4];
        #pragma unroll
        for (int j = 0; j < 4; j++) sacc[j] = zero4();
        #pragma unroll
        for (int c = 0; c < 2; c++) {
            bf16x8 bk4[4];
            #pragma unroll
            for (int j = 0; j < 4; j++) {
                const int pc = ((c * 4 + quad) ^ s7) * 8;
                bk4[j] = ldfrag(Ks + (j * 16 + l15) * LDSW + pc);
            }
            #pragma unroll
            for (int j = 0; j < 4; j++)
                sacc[j] = __builtin_amdgcn_mfma_f32_16x16x32_bf16(
                    bk4[j], aQ[c], sacc[j], 0, 0, 0);
        }

        // exp2 + scalar row-sum + PACKED P write: per j, keys j*16+quad*4+..+3
        // are consecutive -> one u64 (2 fused cvt_pk) per j, 4 writes total.
        #pragma unroll
        for (int j = 0; j < 4; j++) {
            float e0 = exp2f(sacc[j][0]);
            float e1 = exp2f(sacc[j][1]);
            float e2 = exp2f(sacc[j][2]);
            float e3 = exp2f(sacc[j][3]);
            l_acc += (e0 + e1) + (e2 + e3);
            union { bf16_t h[4]; unsigned long long u; } pk;
            pk.h[0] = (bf16_t)e0; pk.h[1] = (bf16_t)e1;
            pk.h[2] = (bf16_t)e2; pk.h[3] = (bf16_t)e3;
            const int Lc = j * 2 + (quad >> 1);          // logical 16B chunk
            *reinterpret_cast<unsigned long long*>(
                prow + ((Lc ^ s7) << 3) + ((quad & 1) << 2)) = pk.u;
        }

        // O += P*V (same-wave LDS write->read; compiler inserts lgkmcnt wait)
        #pragma unroll
        for (int c = 0; c < 2; c++) {
            bf16x8 ap = ldfrag(prow + (((c * 4 + quad) ^ s7) << 3));
            bf16x8 bv4[4];
            #pragma unroll
            for (int j = 0; j < 4; j++) {
                const int pc = ((c * 4 + quad) ^ s7) * 8;
                bv4[j] = ldfrag(Vts + (j * 16 + l15) * LDSW + pc);
            }
            #pragma unroll
            for (int j = 0; j < 4; j++)
                oacc[j] = __builtin_amdgcn_mfma_f32_16x16x32_bf16(
                    ap, bv4[j], oacc[j], 0, 0, 0);
        }
    }

    // normalize: l_acc holds partial sum for q=l15 over this quad's keys;
    // reduce over the 4 quads (lanes l15, l15+16, l15+32, l15+48)
    float l = l_acc;
    l += __shfl_xor(l, 16, 64);
    l += __shfl_xor(l, 32, 64);

    const int pch = l15 >> 3, pwi = l15 & 7;
    #pragma unroll
    for (int r = 0; r < 4; r++) {
        // O row q = wid*16+quad*4+r; its row-sum lives at lane l15==quad*4+r
        float lr = __shfl(l, quad * 4 + r, 16);
        float inv = 1.0f / lr;
        bf16_t* orow = Pls + (wid * 16 + quad * 4 + r) * LDSW;
        const int rx = (quad * 4 + r) & 7;
        #pragma unroll
        for (int j = 0; j < 4; j++)
            orow[((pch + 2 * j) ^ rx) * 8 + pwi] = (bf16_t)(oacc[j][r] * inv);
    }
    __syncthreads();

    const int b = bh >> 4, h = bh & 15;
    #pragma unroll
    for (int c = tid; c < 512; c += 256) {   // 64 rows x 8 chunks of 8 bf16
        int row = c >> 3, chunk = c & 7;
        uint4 val = *reinterpret_cast<const uint4*>(
            Pls + row * LDSW + ((chunk ^ (row & 7)) << 3));
        *reinterpret_cast<uint4*>(Oc + ((size_t)(b * SEQ + q0 + row)) * D_MODEL + h * DK + (chunk << 3)) = val;
    }
}

extern "C" void kernel_launch(void* const* d_in, const int* in_sizes, int n_in,
                              void* d_out, int out_size, void* d_ws, size_t ws_size,
                              hipStream_t stream) {
    const float* q  = (const float*)d_in[0];
    const float* k  = (const float*)d_in[1];
    const float* v  = (const float*)d_in[2];
    const float* Wq = (const float*)d_in[3];
    const float* bq = (const float*)d_in[4];
    const float* Wk = (const float*)d_in[5];
    const float* bk = (const float*)d_in[6];
    const float* Wv = (const float*)d_in[7];
    const float* bv = (const float*)d_in[8];
    const float* Wo = (const float*)d_in[9];
    const float* bo = (const float*)d_in[10];

    const size_t nx = (size_t)MROWS * D_MODEL;   // 4,194,304
    const size_t nw = (size_t)D_MODEL * D_MODEL; // 1,048,576

    bf16_t* qb  = (bf16_t*)d_ws;
    bf16_t* kb  = qb  + nx;
    bf16_t* vb  = kb  + nx;
    bf16_t* Wqb = vb  + nx;
    bf16_t* Wkb = Wqb + nw;
    bf16_t* Wvb = Wkb + nw;
    bf16_t* Wob = Wvb + nw;
    bf16_t* Qh  = Wob + nw;   // [BH][S][DK]
    bf16_t* Kh  = Qh  + nx;   // [BH][S][DK]
    bf16_t* Vt  = Kh  + nx;   // [BH][DK][S]
    bf16_t* Oc  = Vt  + nx;   // [B*S][D]

    pack7<<<dim3(4096, 7), 256, 0, stream>>>(q, k, v, Wq, Wk, Wv, Wo,
                                             qb, kb, vb, Wqb, Wkb, Wvb, Wob);

    proj_gemm<<<dim3(8, 32, 3), 256, 0, stream>>>(qb, kb, vb, Wqb, Wkb, Wvb, bq, bk, bv, Qh, Kh, Vt);
    attn_kernel<<<dim3(32, 32), 256, 0, stream>>>(Qh, Kh, Vt, Oc);
    out_gemm<<<dim3(8, 64), 256, 0, stream>>>(Oc, Wob, bo, (float*)d_out);
}

// Round 6
// 235.094 us; speedup vs baseline: 1.1124x; 1.0190x over previous
//
#include <hip/hip_runtime.h>
#include <hip/hip_bf16.h>
#include <math.h>

// ---- types ----
typedef __bf16 bf16_t;
typedef bf16_t bf16x8 __attribute__((ext_vector_type(8)));
typedef float f32x4 __attribute__((ext_vector_type(4)));

#define D_MODEL 1024
#define NH 16
#define DK 64
#define SEQ 2048
#define MROWS 4096   // B*S
#define LDSW 64      // UNPADDED row width for async-DMA tiles (XOR-swizzled)
#define LDC 136      // padded row for the 128x128 epilogue staging tile

__device__ __forceinline__ bf16x8 ldfrag(const bf16_t* p) {
    union { uint4 u; bf16x8 v; } c;
    c.u = *reinterpret_cast<const uint4*>(p);
    return c.v;
}

__device__ __forceinline__ f32x4 zero4() { f32x4 z = {0.f, 0.f, 0.f, 0.f}; return z; }

// async global->LDS DMA, 16B per lane. LDS dest = wave-uniform base + lane*16.
__device__ __forceinline__ void gll16(const bf16_t* g, bf16_t* l) {
    __builtin_amdgcn_global_load_lds(
        (const __attribute__((address_space(1))) unsigned int*)g,
        (__attribute__((address_space(3))) unsigned int*)l,
        16, 0, 0);
}

// ---- fp32 -> bf16 pack, all 7 tensors in one launch ----
__global__ void pack7(const float* __restrict__ q, const float* __restrict__ k,
                      const float* __restrict__ v, const float* __restrict__ wq,
                      const float* __restrict__ wk, const float* __restrict__ wv,
                      const float* __restrict__ wo,
                      bf16_t* __restrict__ dq, bf16_t* __restrict__ dk,
                      bf16_t* __restrict__ dv, bf16_t* __restrict__ dwq,
                      bf16_t* __restrict__ dwk, bf16_t* __restrict__ dwv,
                      bf16_t* __restrict__ dwo) {
    const int y = blockIdx.y;
    if (y >= 3 && blockIdx.x >= 1024) return;   // weights are 1/4 the size
    const float* s;
    bf16_t* d;
    switch (y) {
        case 0: s = q;  d = dq;  break;
        case 1: s = k;  d = dk;  break;
        case 2: s = v;  d = dv;  break;
        case 3: s = wq; d = dwq; break;
        case 4: s = wk; d = dwk; break;
        case 5: s = wv; d = dwv; break;
        default: s = wo; d = dwo; break;
    }
    int i = (blockIdx.x * blockDim.x + threadIdx.x) * 4;
    float4 f = *reinterpret_cast<const float4*>(s + i);
    union { bf16_t h[4]; uint2 u; } o;
    o.h[0] = (bf16_t)f.x; o.h[1] = (bf16_t)f.y; o.h[2] = (bf16_t)f.z; o.h[3] = (bf16_t)f.w;
    *reinterpret_cast<uint2*>(d + i) = o.u;
}

// ---- shared GEMM core: C(128x128) = A(rowmaj MxK) * B(rowmaj NxK)^T ----
// m97 structure: async global_load_lds staging; unpadded [128][64] tiles with
// XOR 16B-chunk swizzle (phys chunk p of row r holds logical chunk p^(r&7)).
__device__ __forceinline__ void gemm_core(
    const bf16_t* __restrict__ A, const bf16_t* __restrict__ Bm,
    int K, int m0, int n0,
    bf16_t* As, bf16_t* Bs,       // each 128*LDSW bf16
    f32x4 acc[4][4]) {

    const int tid = threadIdx.x;
    const int lane = tid & 63;
    const int wid = tid >> 6;
    const int wm = (wid >> 1) * 64, wn = (wid & 1) * 64;
    const int l15 = lane & 15, quad = lane >> 4;

    const int lrow   = lane >> 3;                // 0..7 row within 8-row group
    const int gcol   = ((lane & 7) ^ lrow) * 8;  // swizzled logical col (elems)

    #pragma unroll
    for (int i = 0; i < 4; i++)
        #pragma unroll
        for (int j = 0; j < 4; j++) acc[i][j] = zero4();

    for (int k0 = 0; k0 < K; k0 += 64) {
        __syncthreads();
        #pragma unroll
        for (int t = 0; t < 4; t++) {
            const int rbase = wid * 32 + t * 8;
            gll16(A  + (size_t)(m0 + rbase + lrow) * K + k0 + gcol, As + rbase * LDSW);
            gll16(Bm + (size_t)(n0 + rbase + lrow) * K + k0 + gcol, Bs + rbase * LDSW);
        }
        __syncthreads();
        #pragma unroll
        for (int c = 0; c < 2; c++) {
            bf16x8 af[4], bfr[4];
            #pragma unroll
            for (int i = 0; i < 4; i++) {
                const int row = wm + i * 16 + l15;
                const int pc = ((c * 4 + quad) ^ (l15 & 7)) * 8;
                af[i] = ldfrag(As + row * LDSW + pc);
            }
            #pragma unroll
            for (int j = 0; j < 4; j++) {
                const int row = wn + j * 16 + l15;
                const int pc = ((c * 4 + quad) ^ (l15 & 7)) * 8;
                bfr[j] = ldfrag(Bs + row * LDSW + pc);
            }
            #pragma unroll
            for (int i = 0; i < 4; i++)
                #pragma unroll
                for (int j = 0; j < 4; j++)
                    acc[i][j] = __builtin_amdgcn_mfma_f32_16x16x32_bf16(af[i], bfr[j], acc[i][j], 0, 0, 0);
        }
    }
}

// ---- fused Q/K/V projection: blockIdx.z picks which ----
__global__ __launch_bounds__(256, 3) void proj_gemm(
    const bf16_t* __restrict__ qb, const bf16_t* __restrict__ kb,
    const bf16_t* __restrict__ vb,
    const bf16_t* __restrict__ Wq, const bf16_t* __restrict__ Wk,
    const bf16_t* __restrict__ Wv,
    const float* __restrict__ bq, const float* __restrict__ bk, const float* __restrict__ bv,
    bf16_t* __restrict__ Qh, bf16_t* __restrict__ Kh, bf16_t* __restrict__ Vt) {

    __shared__ __align__(16) bf16_t sm[128 * LDC];   // 34816B: As|Bs, reused as Cs
    bf16_t* As = sm;
    bf16_t* Bs = sm + 128 * LDSW;
    bf16_t (*Cs)[LDC] = reinterpret_cast<bf16_t(*)[LDC]>(sm);
    f32x4 acc[4][4];

    const int mode = blockIdx.z;
    const bf16_t* X = (mode == 0) ? qb : (mode == 1) ? kb : vb;
    const bf16_t* W = (mode == 0) ? Wq : (mode == 1) ? Wk : Wv;
    const float* bias = (mode == 0) ? bq : (mode == 1) ? bk : bv;
    const int m0 = blockIdx.y * 128, n0 = blockIdx.x * 128;

    gemm_core(X, W, D_MODEL, m0, n0, As, Bs, acc);

    const int tid = threadIdx.x, lane = tid & 63, wid = tid >> 6;
    const int wm = (wid >> 1) * 64, wn = (wid & 1) * 64;
    const int l15 = lane & 15, quad = lane >> 4;

    __syncthreads();
    if (mode != 2) {
        // Q gets 1/sqrt(dk) * log2(e) folded in so attn can use raw exp2
        const float sc = (mode == 0) ? 0.125f * 1.44269504f : 1.0f;
        #pragma unroll
        for (int i = 0; i < 4; i++)
            #pragma unroll
            for (int j = 0; j < 4; j++)
                #pragma unroll
                for (int r = 0; r < 4; r++) {
                    int gn = n0 + wn + j * 16 + l15;
                    Cs[wm + i * 16 + quad * 4 + r][wn + j * 16 + l15] =
                        (bf16_t)((acc[i][j][r] + bias[gn]) * sc);
                }
    } else {
        #pragma unroll
        for (int i = 0; i < 4; i++)
            #pragma unroll
            for (int j = 0; j < 4; j++)
                #pragma unroll
                for (int r = 0; r < 4; r++) {
                    int gn = n0 + wn + j * 16 + l15;
                    Cs[wn + j * 16 + l15][wm + i * 16 + quad * 4 + r] =
                        (bf16_t)(acc[i][j][r] + bias[gn]);
                }
    }
    __syncthreads();

    #pragma unroll
    for (int c = tid; c < 2048; c += 256) {
        int row = c >> 4, col8 = (c & 15) << 3;
        uint4 val = *reinterpret_cast<const uint4*>(&Cs[row][col8]);
        if (mode != 2) {
            int gm = m0 + row, gn = n0 + col8;
            int b = gm >> 11, seq = gm & 2047;
            int h = gn >> 6, dk = gn & 63;
            bf16_t* dst = (mode == 0) ? Qh : Kh;
            *reinterpret_cast<uint4*>(dst + ((size_t)(b * NH + h) * SEQ + seq) * DK + dk) = val;
        } else {
            int gn = n0 + row, gm = m0 + col8;
            int b = gm >> 11, seq = gm & 2047;
            int h = gn >> 6, dk = gn & 63;
            *reinterpret_cast<uint4*>(Vt + ((size_t)(b * NH + h) * DK + dk) * SEQ + seq) = val;
        }
    }
}

// ---- output projection: 64x128 tiles for TLP ----
__global__ __launch_bounds__(256, 2) void out_gemm(
    const bf16_t* __restrict__ Oc, const bf16_t* __restrict__ Wo,
    const float* __restrict__ bo, float* __restrict__ Cout) {

    __shared__ __align__(16) bf16_t As[64 * LDSW];    // 64 M-rows
    __shared__ __align__(16) bf16_t Bs[128 * LDSW];   // 128 N-rows
    f32x4 acc[2][4];
    const int m0 = blockIdx.y * 64, n0 = blockIdx.x * 128;

    const int tid = threadIdx.x;
    const int lane = tid & 63;
    const int wid = tid >> 6;
    const int wm = (wid >> 1) * 32, wn = (wid & 1) * 64;
    const int l15 = lane & 15, quad = lane >> 4;
    const int lrow = lane >> 3;
    const int gcol = ((lane & 7) ^ lrow) * 8;

    #pragma unroll
    for (int i = 0; i < 2; i++)
        #pragma unroll
        for (int j = 0; j < 4; j++) acc[i][j] = zero4();

    for (int k0 = 0; k0 < D_MODEL; k0 += 64) {
        __syncthreads();
        // A: 64 rows -> 2 gll16/wave; B: 128 rows -> 4 gll16/wave
        #pragma unroll
        for (int t = 0; t < 2; t++) {
            const int rbase = wid * 16 + t * 8;
            gll16(Oc + (size_t)(m0 + rbase + lrow) * D_MODEL + k0 + gcol, As + rbase * LDSW);
        }
        #pragma unroll
        for (int t = 0; t < 4; t++) {
            const int rbase = wid * 32 + t * 8;
            gll16(Wo + (size_t)(n0 + rbase + lrow) * D_MODEL + k0 + gcol, Bs + rbase * LDSW);
        }
        __syncthreads();
        #pragma unroll
        for (int c = 0; c < 2; c++) {
            bf16x8 af[2], bfr[4];
            #pragma unroll
            for (int i = 0; i < 2; i++) {
                const int row = wm + i * 16 + l15;
                const int pc = ((c * 4 + quad) ^ (l15 & 7)) * 8;
                af[i] = ldfrag(As + row * LDSW + pc);
            }
            #pragma unroll
            for (int j = 0; j < 4; j++) {
                const int row = wn + j * 16 + l15;
                const int pc = ((c * 4 + quad) ^ (l15 & 7)) * 8;
                bfr[j] = ldfrag(Bs + row * LDSW + pc);
            }
            #pragma unroll
            for (int i = 0; i < 2; i++)
                #pragma unroll
                for (int j = 0; j < 4; j++)
                    acc[i][j] = __builtin_amdgcn_mfma_f32_16x16x32_bf16(af[i], bfr[j], acc[i][j], 0, 0, 0);
        }
    }

    #pragma unroll
    for (int i = 0; i < 2; i++)
        #pragma unroll
        for (int j = 0; j < 4; j++)
            #pragma unroll
            for (int r = 0; r < 4; r++) {
                int gm = m0 + wm + i * 16 + quad * 4 + r;
                int gn = n0 + wn + j * 16 + l15;
                Cout[(size_t)gm * D_MODEL + gn] = acc[i][j][r] + bo[gn];
            }
}

// ---- flash attention: one block = one (b,h) x 64-query tile; 64-key tiles ----
// R15: ZERO-SHUFFLE PV. The key axis inside a 64-key tile is a free
// permutation (keys are summed over) as long as K-staging and V-consumption
// agree. After swapped QK^T, lane(q=l15,quad) holds S for K-tile slots
// {j*16+quad*4+r}; PV-swapped (O^T = V^T * P^T) needs slots {c*32+quad*8+i}
// at the same lane. Staging K-tile row s from global key k0 + sigma(s),
//   sigma(s) = (s>>5)<<5 | ((s>>2)&3)<<3 | ((s>>4)&1)<<2 | (s&3),
// makes these two sets coincide lane-wise: the PV B-fragment is
//   pb[c] = pack_bf16(exp2(sacc[2c][0..3]), exp2(sacc[2c+1][0..3]))
// built ENTIRELY in-register. Deletes the whole P LDS round-trip (4
// ds_write_b64 + 2 ds_read_b128 + lgkm chain + 2.1M conflict cycles/disp).
// V^T fragments move to the A-operand (same addresses as before). Output is
// O^T: lane holds O[q=l15][d=j'*16+quad*4+r]; inv is lane-local (no shfl
// broadcast); single O staging write at the end.
__global__ __launch_bounds__(256) void attn_kernel(
    const bf16_t* __restrict__ Qh, const bf16_t* __restrict__ Kh,
    const bf16_t* __restrict__ Vt, bf16_t* __restrict__ Oc) {

    __shared__ __align__(16) bf16_t Ks[64 * LDSW];    // K tile [slot][dk], sigma-ordered rows
    __shared__ __align__(16) bf16_t Vts[64 * LDSW];   // V^T tile [dk][key], natural order
    __shared__ __align__(16) bf16_t Pls[64 * LDSW];   // O epilogue staging only

    const int tid = threadIdx.x, lane = tid & 63, wid = tid >> 6;
    const int l15 = lane & 15, quad = lane >> 4;
    const int bh = blockIdx.x;                 // XCD-friendly
    const int q0 = blockIdx.y * 64;
    const bf16_t* Qbase = Qh + (size_t)bh * SEQ * DK;
    const bf16_t* Kbase = Kh + (size_t)bh * SEQ * DK;
    const bf16_t* Vbase = Vt + (size_t)bh * DK * SEQ;

    const int lrow = lane >> 3;                  // 0..7 row within 8-row group
    const int gcol = ((lane & 7) ^ lrow) * 8;    // swizzled logical col (elems)

    // Q fragments: wave wid owns query rows [q0+wid*16, +16)
    bf16x8 aQ[2];
    #pragma unroll
    for (int c = 0; c < 2; c++)
        aQ[c] = ldfrag(Qbase + (size_t)(q0 + wid * 16 + l15) * DK + c * 32 + quad * 8);

    f32x4 oacc[4];
    #pragma unroll
    for (int j = 0; j < 4; j++) oacc[j] = zero4();
    float l_acc = 0.f;

    const int s7 = l15 & 7;

    for (int kt = 0; kt < SEQ / 64; kt++) {
        const int k0 = kt * 64;
        __syncthreads();   // prev-iter reads of Ks/Vts done
        // wave wid stages rows [wid*16, wid*16+16) of both tiles (2+2 DMA
        // insts). K rows sigma-permuted via the per-lane GLOBAL address
        // (LDS dest must stay linear for the DMA).
        #pragma unroll
        for (int t = 0; t < 2; t++) {
            const int rbase = wid * 16 + t * 8;
            const int srow = rbase + lrow;       // tile slot 0..63
            const int sigma = ((srow >> 5) << 5) | (((srow >> 2) & 3) << 3) |
                              (((srow >> 4) & 1) << 2) | (srow & 3);
            gll16(Kbase + (size_t)(k0 + sigma) * DK + gcol,      Ks  + rbase * LDSW);
            gll16(Vbase + (size_t)(rbase + lrow) * SEQ + k0 + gcol, Vts + rbase * LDSW);
        }
        __syncthreads();   // barrier drains vmcnt -> DMA complete

        // S^T = K*Q^T (Q pre-scaled by log2e/8); slots sigma-ordered.
        // sacc[j][r] = S[slot j*16+quad*4+r][q = q0+wid*16+l15]
        f32x4 sacc[4];
        #pragma unroll
        for (int j = 0; j < 4; j++) sacc[j] = zero4();
        #pragma unroll
        for (int c = 0; c < 2; c++) {
            bf16x8 bk4[4];
            #pragma unroll
            for (int j = 0; j < 4; j++) {
                const int pc = ((c * 4 + quad) ^ s7) * 8;
                bk4[j] = ldfrag(Ks + (j * 16 + l15) * LDSW + pc);
            }
            #pragma unroll
            for (int j = 0; j < 4; j++)
                sacc[j] = __builtin_amdgcn_mfma_f32_16x16x32_bf16(
                    bk4[j], aQ[c], sacc[j], 0, 0, 0);
        }

        // exp2 + row-sum + in-register P^T fragments (no LDS!):
        // pb[c] elements i: slot c*32+quad*8+i = global key via sigma =
        // exp2(sacc[2c + (i>>2)][i&3]) — exactly this lane's registers.
        bf16x8 pb[2];
        #pragma unroll
        for (int c = 0; c < 2; c++) {
            union { bf16_t h[8]; bf16x8 v; } pk;
            #pragma unroll
            for (int half = 0; half < 2; half++) {
                const int j = c * 2 + half;
                float e0 = exp2f(sacc[j][0]);
                float e1 = exp2f(sacc[j][1]);
                float e2 = exp2f(sacc[j][2]);
                float e3 = exp2f(sacc[j][3]);
                l_acc += (e0 + e1) + (e2 + e3);
                pk.h[half * 4 + 0] = (bf16_t)e0;
                pk.h[half * 4 + 1] = (bf16_t)e1;
                pk.h[half * 4 + 2] = (bf16_t)e2;
                pk.h[half * 4 + 3] = (bf16_t)e3;
            }
            pb[c] = pk.v;
        }

        // O^T += V^T * P^T : A = V^T fragment (rows d = j'*16+l15, k = key
        // chunk), B = pb[c]. oacc[j'][r] = O[q=l15][d=j'*16+quad*4+r].
        #pragma unroll
        for (int c = 0; c < 2; c++) {
            bf16x8 av[4];
            #pragma unroll
            for (int j = 0; j < 4; j++) {
                const int pc = ((c * 4 + quad) ^ s7) * 8;
                av[j] = ldfrag(Vts + (j * 16 + l15) * LDSW + pc);
            }
            #pragma unroll
            for (int j = 0; j < 4; j++)
                oacc[j] = __builtin_amdgcn_mfma_f32_16x16x32_bf16(
                    av[j], pb[c], oacc[j], 0, 0, 0);
        }
    }

    // normalize: l_acc is the partial sum for q=l15 over this quad's keys;
    // reduce across quads (lanes l15, l15+16, l15+32, l15+48). inv is then
    // lane-local (this lane's own q).
    float l = l_acc;
    l += __shfl_xor(l, 16, 64);
    l += __shfl_xor(l, 32, 64);
    const float inv = 1.0f / l;

    // stage O (row q = wid*16+l15, cols j'*16+quad*4+r) into Pls, swizzled
    bf16_t* orow = Pls + (wid * 16 + l15) * LDSW;
    #pragma unroll
    for (int jp = 0; jp < 4; jp++) {
        union { bf16_t h[4]; unsigned long long u; } pk;
        pk.h[0] = (bf16_t)(oacc[jp][0] * inv);
        pk.h[1] = (bf16_t)(oacc[jp][1] * inv);
        pk.h[2] = (bf16_t)(oacc[jp][2] * inv);
        pk.h[3] = (bf16_t)(oacc[jp][3] * inv);
        const int Lc = jp * 2 + (quad >> 1);         // logical 16B chunk
        *reinterpret_cast<unsigned long long*>(
            orow + ((Lc ^ s7) << 3) + ((quad & 1) << 2)) = pk.u;
    }
    __syncthreads();

    const int b = bh >> 4, h = bh & 15;
    #pragma unroll
    for (int c = tid; c < 512; c += 256) {   // 64 rows x 8 chunks of 8 bf16
        int row = c >> 3, chunk = c & 7;
        uint4 val = *reinterpret_cast<const uint4*>(
            Pls + row * LDSW + ((chunk ^ (row & 7)) << 3));
        *reinterpret_cast<uint4*>(Oc + ((size_t)(b * SEQ + q0 + row)) * D_MODEL + h * DK + (chunk << 3)) = val;
    }
}

extern "C" void kernel_launch(void* const* d_in, const int* in_sizes, int n_in,
                              void* d_out, int out_size, void* d_ws, size_t ws_size,
                              hipStream_t stream) {
    const float* q  = (const float*)d_in[0];
    const float* k  = (const float*)d_in[1];
    const float* v  = (const float*)d_in[2];
    const float* Wq = (const float*)d_in[3];
    const float* bq = (const float*)d_in[4];
    const float* Wk = (const float*)d_in[5];
    const float* bk = (const float*)d_in[6];
    const float* Wv = (const float*)d_in[7];
    const float* bv = (const float*)d_in[8];
    const float* Wo = (const float*)d_in[9];
    const float* bo = (const float*)d_in[10];

    const size_t nx = (size_t)MROWS * D_MODEL;   // 4,194,304
    const size_t nw = (size_t)D_MODEL * D_MODEL; // 1,048,576

    bf16_t* qb  = (bf16_t*)d_ws;
    bf16_t* kb  = qb  + nx;
    bf16_t* vb  = kb  + nx;
    bf16_t* Wqb = vb  + nx;
    bf16_t* Wkb = Wqb + nw;
    bf16_t* Wvb = Wkb + nw;
    bf16_t* Wob = Wvb + nw;
    bf16_t* Qh  = Wob + nw;   // [BH][S][DK]
    bf16_t* Kh  = Qh  + nx;   // [BH][S][DK]
    bf16_t* Vt  = Kh  + nx;   // [BH][DK][S]
    bf16_t* Oc  = Vt  + nx;   // [B*S][D]

    pack7<<<dim3(4096, 7), 256, 0, stream>>>(q, k, v, Wq, Wk, Wv, Wo,
                                             qb, kb, vb, Wqb, Wkb, Wvb, Wob);

    proj_gemm<<<dim3(8, 32, 3), 256, 0, stream>>>(qb, kb, vb, Wqb, Wkb, Wvb, bq, bk, bv, Qh, Kh, Vt);
    attn_kernel<<<dim3(32, 32), 256, 0, stream>>>(Qh, Kh, Vt, Oc);
    out_gemm<<<dim3(8, 64), 256, 0, stream>>>(Oc, Wob, bo, (float*)d_out);
}

// Round 7
// 222.790 us; speedup vs baseline: 1.1739x; 1.0552x over previous
//
#include <hip/hip_runtime.h>
#include <hip/hip_bf16.h>
#include <math.h>

// ---- types ----
typedef __bf16 bf16_t;
typedef bf16_t bf16x8 __attribute__((ext_vector_type(8)));
typedef float f32x4 __attribute__((ext_vector_type(4)));

#define D_MODEL 1024
#define NH 16
#define DK 64
#define SEQ 2048
#define MROWS 4096   // B*S
#define LDSW 64      // UNPADDED row width for async-DMA tiles (XOR-swizzled)
#define LDC 136      // padded row for the 128x128 epilogue staging tile

__device__ __forceinline__ bf16x8 ldfrag(const bf16_t* p) {
    union { uint4 u; bf16x8 v; } c;
    c.u = *reinterpret_cast<const uint4*>(p);
    return c.v;
}

__device__ __forceinline__ f32x4 zero4() { f32x4 z = {0.f, 0.f, 0.f, 0.f}; return z; }

// async global->LDS DMA, 16B per lane. LDS dest = wave-uniform base + lane*16.
__device__ __forceinline__ void gll16(const bf16_t* g, bf16_t* l) {
    __builtin_amdgcn_global_load_lds(
        (const __attribute__((address_space(1))) unsigned int*)g,
        (__attribute__((address_space(3))) unsigned int*)l,
        16, 0, 0);
}

// ---- fp32 -> bf16 pack, all 7 tensors in one launch; 8 floats/thread ----
__global__ void pack7(const float* __restrict__ q, const float* __restrict__ k,
                      const float* __restrict__ v, const float* __restrict__ wq,
                      const float* __restrict__ wk, const float* __restrict__ wv,
                      const float* __restrict__ wo,
                      bf16_t* __restrict__ dq, bf16_t* __restrict__ dk,
                      bf16_t* __restrict__ dv, bf16_t* __restrict__ dwq,
                      bf16_t* __restrict__ dwk, bf16_t* __restrict__ dwv,
                      bf16_t* __restrict__ dwo) {
    const int y = blockIdx.y;
    if (y >= 3 && blockIdx.x >= 512) return;   // weights are 1/4 the size
    const float* s;
    bf16_t* d;
    switch (y) {
        case 0: s = q;  d = dq;  break;
        case 1: s = k;  d = dk;  break;
        case 2: s = v;  d = dv;  break;
        case 3: s = wq; d = dwq; break;
        case 4: s = wk; d = dwk; break;
        case 5: s = wv; d = dwv; break;
        default: s = wo; d = dwo; break;
    }
    int i = (blockIdx.x * blockDim.x + threadIdx.x) * 8;
    float4 f0 = *reinterpret_cast<const float4*>(s + i);
    float4 f1 = *reinterpret_cast<const float4*>(s + i + 4);
    union { bf16_t h[8]; uint4 u; } o;
    o.h[0] = (bf16_t)f0.x; o.h[1] = (bf16_t)f0.y; o.h[2] = (bf16_t)f0.z; o.h[3] = (bf16_t)f0.w;
    o.h[4] = (bf16_t)f1.x; o.h[5] = (bf16_t)f1.y; o.h[6] = (bf16_t)f1.z; o.h[7] = (bf16_t)f1.w;
    *reinterpret_cast<uint4*>(d + i) = o.u;
}

// ---- shared GEMM core: C(128x128) = A(rowmaj MxK) * B(rowmaj NxK)^T ----
// m97 structure: async global_load_lds staging; unpadded [128][64] tiles with
// XOR 16B-chunk swizzle (phys chunk p of row r holds logical chunk p^(r&7)).
__device__ __forceinline__ void gemm_core(
    const bf16_t* __restrict__ A, const bf16_t* __restrict__ Bm,
    int K, int m0, int n0,
    bf16_t* As, bf16_t* Bs,       // each 128*LDSW bf16
    f32x4 acc[4][4]) {

    const int tid = threadIdx.x;
    const int lane = tid & 63;
    const int wid = tid >> 6;
    const int wm = (wid >> 1) * 64, wn = (wid & 1) * 64;
    const int l15 = lane & 15, quad = lane >> 4;

    const int lrow   = lane >> 3;                // 0..7 row within 8-row group
    const int gcol   = ((lane & 7) ^ lrow) * 8;  // swizzled logical col (elems)

    #pragma unroll
    for (int i = 0; i < 4; i++)
        #pragma unroll
        for (int j = 0; j < 4; j++) acc[i][j] = zero4();

    for (int k0 = 0; k0 < K; k0 += 64) {
        __syncthreads();
        #pragma unroll
        for (int t = 0; t < 4; t++) {
            const int rbase = wid * 32 + t * 8;
            gll16(A  + (size_t)(m0 + rbase + lrow) * K + k0 + gcol, As + rbase * LDSW);
            gll16(Bm + (size_t)(n0 + rbase + lrow) * K + k0 + gcol, Bs + rbase * LDSW);
        }
        __syncthreads();
        #pragma unroll
        for (int c = 0; c < 2; c++) {
            bf16x8 af[4], bfr[4];
            #pragma unroll
            for (int i = 0; i < 4; i++) {
                const int row = wm + i * 16 + l15;
                const int pc = ((c * 4 + quad) ^ (l15 & 7)) * 8;
                af[i] = ldfrag(As + row * LDSW + pc);
            }
            #pragma unroll
            for (int j = 0; j < 4; j++) {
                const int row = wn + j * 16 + l15;
                const int pc = ((c * 4 + quad) ^ (l15 & 7)) * 8;
                bfr[j] = ldfrag(Bs + row * LDSW + pc);
            }
            #pragma unroll
            for (int i = 0; i < 4; i++)
                #pragma unroll
                for (int j = 0; j < 4; j++)
                    acc[i][j] = __builtin_amdgcn_mfma_f32_16x16x32_bf16(af[i], bfr[j], acc[i][j], 0, 0, 0);
        }
    }
}

// ---- fused Q/K/V projection: blockIdx.z picks which ----
__global__ __launch_bounds__(256, 3) void proj_gemm(
    const bf16_t* __restrict__ qb, const bf16_t* __restrict__ kb,
    const bf16_t* __restrict__ vb,
    const bf16_t* __restrict__ Wq, const bf16_t* __restrict__ Wk,
    const bf16_t* __restrict__ Wv,
    const float* __restrict__ bq, const float* __restrict__ bk, const float* __restrict__ bv,
    bf16_t* __restrict__ Qh, bf16_t* __restrict__ Kh, bf16_t* __restrict__ Vt) {

    __shared__ __align__(16) bf16_t sm[128 * LDC];   // 34816B: As|Bs, reused as Cs
    bf16_t* As = sm;
    bf16_t* Bs = sm + 128 * LDSW;
    bf16_t (*Cs)[LDC] = reinterpret_cast<bf16_t(*)[LDC]>(sm);
    f32x4 acc[4][4];

    const int mode = blockIdx.z;
    const bf16_t* X = (mode == 0) ? qb : (mode == 1) ? kb : vb;
    const bf16_t* W = (mode == 0) ? Wq : (mode == 1) ? Wk : Wv;
    const float* bias = (mode == 0) ? bq : (mode == 1) ? bk : bv;
    const int m0 = blockIdx.y * 128, n0 = blockIdx.x * 128;

    gemm_core(X, W, D_MODEL, m0, n0, As, Bs, acc);

    const int tid = threadIdx.x, lane = tid & 63, wid = tid >> 6;
    const int wm = (wid >> 1) * 64, wn = (wid & 1) * 64;
    const int l15 = lane & 15, quad = lane >> 4;

    __syncthreads();
    if (mode != 2) {
        // Q gets 1/sqrt(dk) * log2(e) folded in so attn can use raw exp2
        const float sc = (mode == 0) ? 0.125f * 1.44269504f : 1.0f;
        #pragma unroll
        for (int i = 0; i < 4; i++)
            #pragma unroll
            for (int j = 0; j < 4; j++)
                #pragma unroll
                for (int r = 0; r < 4; r++) {
                    int gn = n0 + wn + j * 16 + l15;
                    Cs[wm + i * 16 + quad * 4 + r][wn + j * 16 + l15] =
                        (bf16_t)((acc[i][j][r] + bias[gn]) * sc);
                }
    } else {
        #pragma unroll
        for (int i = 0; i < 4; i++)
            #pragma unroll
            for (int j = 0; j < 4; j++)
                #pragma unroll
                for (int r = 0; r < 4; r++) {
                    int gn = n0 + wn + j * 16 + l15;
                    Cs[wn + j * 16 + l15][wm + i * 16 + quad * 4 + r] =
                        (bf16_t)(acc[i][j][r] + bias[gn]);
                }
    }
    __syncthreads();

    #pragma unroll
    for (int c = tid; c < 2048; c += 256) {
        int row = c >> 4, col8 = (c & 15) << 3;
        uint4 val = *reinterpret_cast<const uint4*>(&Cs[row][col8]);
        if (mode != 2) {
            int gm = m0 + row, gn = n0 + col8;
            int b = gm >> 11, seq = gm & 2047;
            int h = gn >> 6, dk = gn & 63;
            bf16_t* dst = (mode == 0) ? Qh : Kh;
            *reinterpret_cast<uint4*>(dst + ((size_t)(b * NH + h) * SEQ + seq) * DK + dk) = val;
        } else {
            int gn = n0 + row, gm = m0 + col8;
            int b = gm >> 11, seq = gm & 2047;
            int h = gn >> 6, dk = gn & 63;
            *reinterpret_cast<uint4*>(Vt + ((size_t)(b * NH + h) * DK + dk) * SEQ + seq) = val;
        }
    }
}

// ---- output projection: 64x128 tiles for TLP ----
__global__ __launch_bounds__(256, 2) void out_gemm(
    const bf16_t* __restrict__ Oc, const bf16_t* __restrict__ Wo,
    const float* __restrict__ bo, float* __restrict__ Cout) {

    __shared__ __align__(16) bf16_t As[64 * LDSW];    // 64 M-rows
    __shared__ __align__(16) bf16_t Bs[128 * LDSW];   // 128 N-rows
    f32x4 acc[2][4];
    const int m0 = blockIdx.y * 64, n0 = blockIdx.x * 128;

    const int tid = threadIdx.x;
    const int lane = tid & 63;
    const int wid = tid >> 6;
    const int wm = (wid >> 1) * 32, wn = (wid & 1) * 64;
    const int l15 = lane & 15, quad = lane >> 4;
    const int lrow = lane >> 3;
    const int gcol = ((lane & 7) ^ lrow) * 8;

    #pragma unroll
    for (int i = 0; i < 2; i++)
        #pragma unroll
        for (int j = 0; j < 4; j++) acc[i][j] = zero4();

    for (int k0 = 0; k0 < D_MODEL; k0 += 64) {
        __syncthreads();
        // A: 64 rows -> 2 gll16/wave; B: 128 rows -> 4 gll16/wave
        #pragma unroll
        for (int t = 0; t < 2; t++) {
            const int rbase = wid * 16 + t * 8;
            gll16(Oc + (size_t)(m0 + rbase + lrow) * D_MODEL + k0 + gcol, As + rbase * LDSW);
        }
        #pragma unroll
        for (int t = 0; t < 4; t++) {
            const int rbase = wid * 32 + t * 8;
            gll16(Wo + (size_t)(n0 + rbase + lrow) * D_MODEL + k0 + gcol, Bs + rbase * LDSW);
        }
        __syncthreads();
        #pragma unroll
        for (int c = 0; c < 2; c++) {
            bf16x8 af[2], bfr[4];
            #pragma unroll
            for (int i = 0; i < 2; i++) {
                const int row = wm + i * 16 + l15;
                const int pc = ((c * 4 + quad) ^ (l15 & 7)) * 8;
                af[i] = ldfrag(As + row * LDSW + pc);
            }
            #pragma unroll
            for (int j = 0; j < 4; j++) {
                const int row = wn + j * 16 + l15;
                const int pc = ((c * 4 + quad) ^ (l15 & 7)) * 8;
                bfr[j] = ldfrag(Bs + row * LDSW + pc);
            }
            #pragma unroll
            for (int i = 0; i < 2; i++)
                #pragma unroll
                for (int j = 0; j < 4; j++)
                    acc[i][j] = __builtin_amdgcn_mfma_f32_16x16x32_bf16(af[i], bfr[j], acc[i][j], 0, 0, 0);
        }
    }

    #pragma unroll
    for (int i = 0; i < 2; i++)
        #pragma unroll
        for (int j = 0; j < 4; j++)
            #pragma unroll
            for (int r = 0; r < 4; r++) {
                int gm = m0 + wm + i * 16 + quad * 4 + r;
                int gn = n0 + wn + j * 16 + l15;
                Cout[(size_t)gm * D_MODEL + gn] = acc[i][j][r] + bo[gn];
            }
}

// ---- flash attention: one block = one (b,h) x 64-query tile ----
// R16 = R15 (zero-shuffle PV, sigma-permuted K staging) with KVBLK 64->128:
// halves iterations -> halves barriers/drains/loop overhead at identical
// per-key instruction counts. sigma(s) passes bits>=5 through, so the slot
// bijection holds unchanged for c in 0..3 (sacc[8], pb[4]). V^T tile is now
// [64][128] (256B rows) with the full 4-bit chunk XOR (chunk ^ row&15) ->
// PV reads 2-way at worst (free). LDS: K 16K + V 16K = 32K; the O-epilogue
// tile ALIASES Ks (one extra __syncthreads after the loop, else a slow wave
// still in QK would read clobbered Ks). 32K x 4 blocks = 128K <= 160K ->
// occupancy preserved (16 waves/CU). launch_bounds(256,4) pins VGPR <= 128.
__global__ __launch_bounds__(256, 4) void attn_kernel(
    const bf16_t* __restrict__ Qh, const bf16_t* __restrict__ Kh,
    const bf16_t* __restrict__ Vt, bf16_t* __restrict__ Oc) {

    __shared__ __align__(16) bf16_t sma[16384];       // 32 KB
    bf16_t* Ks  = sma;                                // [128][64], sigma rows, chunk^ (row&7)
    bf16_t* Vts = sma + 128 * 64;                     // [64][128], chunk ^ (row&15)
    bf16_t* Pls = sma;                                // O epilogue (aliases Ks)

    const int tid = threadIdx.x, lane = tid & 63, wid = tid >> 6;
    const int l15 = lane & 15, quad = lane >> 4;
    const int bh = blockIdx.x;                 // XCD-friendly
    const int q0 = blockIdx.y * 64;
    const bf16_t* Qbase = Qh + (size_t)bh * SEQ * DK;
    const bf16_t* Kbase = Kh + (size_t)bh * SEQ * DK;
    const bf16_t* Vbase = Vt + (size_t)bh * DK * SEQ;

    const int lrow = lane >> 3;                  // 0..7 row within 8-row group
    const int gcol = ((lane & 7) ^ lrow) * 8;    // K swizzled col (elems)

    // Q fragments: wave wid owns query rows [q0+wid*16, +16)
    bf16x8 aQ[2];
    #pragma unroll
    for (int c = 0; c < 2; c++)
        aQ[c] = ldfrag(Qbase + (size_t)(q0 + wid * 16 + l15) * DK + c * 32 + quad * 8);

    f32x4 oacc[4];
    #pragma unroll
    for (int j = 0; j < 4; j++) oacc[j] = zero4();
    float l_acc = 0.f;

    const int s7 = l15 & 7;
    const int vlrow = lane >> 4;                 // V staging: row within 4-row group
    const int vchk0 = lane & 15;                 // V staging: phys chunk

    for (int kt = 0; kt < SEQ / 128; kt++) {
        const int k0 = kt * 128;
        __syncthreads();   // prev-iter reads of Ks/Vts done
        // K: 128 sigma-permuted rows of 64 (4 gll16/wave);
        // V^T: 64 rows of 128, key-chunk pre-swizzled by row&15 (4 gll16/wave)
        #pragma unroll
        for (int t = 0; t < 4; t++) {
            const int rbase = wid * 32 + t * 8;
            const int srow = rbase + lrow;       // tile slot 0..127
            const int sigma = ((srow >> 5) << 5) | (((srow >> 2) & 3) << 3) |
                              (((srow >> 4) & 1) << 2) | (srow & 3);
            gll16(Kbase + (size_t)(k0 + sigma) * DK + gcol, Ks + rbase * 64);

            const int vrb = wid * 16 + t * 4;    // V^T row base (dk)
            const int vrow = vrb + vlrow;        // 0..63
            gll16(Vbase + (size_t)vrow * SEQ + k0 + ((vchk0 ^ (vrow & 15)) << 3),
                  Vts + vrb * 128);
        }
        __syncthreads();   // barrier drains vmcnt -> DMA complete

        // S^T = K*Q^T (Q pre-scaled by log2e/8); slots sigma-ordered.
        // sacc[j][r] = S[slot j*16+quad*4+r][q = q0+wid*16+l15]
        f32x4 sacc[8];
        #pragma unroll
        for (int j = 0; j < 8; j++) sacc[j] = zero4();
        #pragma unroll
        for (int c = 0; c < 2; c++) {
            bf16x8 bk4[8];
            #pragma unroll
            for (int j = 0; j < 8; j++) {
                const int pc = ((c * 4 + quad) ^ s7) * 8;
                bk4[j] = ldfrag(Ks + (j * 16 + l15) * 64 + pc);
            }
            #pragma unroll
            for (int j = 0; j < 8; j++)
                sacc[j] = __builtin_amdgcn_mfma_f32_16x16x32_bf16(
                    bk4[j], aQ[c], sacc[j], 0, 0, 0);
        }

        // exp2 + row-sum + in-register P^T fragments (no LDS):
        // pb[c] element 4h+r = exp2(sacc[2c+h][r]) = P[key k0+32c+8quad+4h+r]
        bf16x8 pb[4];
        #pragma unroll
        for (int c = 0; c < 4; c++) {
            union { bf16_t h[8]; bf16x8 v; } pk;
            #pragma unroll
            for (int half = 0; half < 2; half++) {
                const int j = c * 2 + half;
                float e0 = exp2f(sacc[j][0]);
                float e1 = exp2f(sacc[j][1]);
                float e2 = exp2f(sacc[j][2]);
                float e3 = exp2f(sacc[j][3]);
                l_acc += (e0 + e1) + (e2 + e3);
                pk.h[half * 4 + 0] = (bf16_t)e0;
                pk.h[half * 4 + 1] = (bf16_t)e1;
                pk.h[half * 4 + 2] = (bf16_t)e2;
                pk.h[half * 4 + 3] = (bf16_t)e3;
            }
            pb[c] = pk.v;
        }

        // O^T += V^T * P^T : A = V^T fragment (rows d = j*16+l15, key chunk
        // (c*4+quad)^l15), B = pb[c]. oacc[j][r] = O[q=l15][d=j*16+quad*4+r]
        #pragma unroll
        for (int c = 0; c < 4; c++) {
            bf16x8 av[4];
            #pragma unroll
            for (int j = 0; j < 4; j++) {
                const int pc = ((c * 4 + quad) ^ l15) * 8;
                av[j] = ldfrag(Vts + (j * 16 + l15) * 128 + pc);
            }
            #pragma unroll
            for (int j = 0; j < 4; j++)
                oacc[j] = __builtin_amdgcn_mfma_f32_16x16x32_bf16(
                    av[j], pb[c], oacc[j], 0, 0, 0);
        }
    }

    // normalize: l_acc is the partial sum for q=l15 over this quad's keys;
    // reduce across quads. inv is lane-local (this lane's own q).
    float l = l_acc;
    l += __shfl_xor(l, 16, 64);
    l += __shfl_xor(l, 32, 64);
    const float inv = 1.0f / l;

    // Pls aliases Ks: every wave must be past its last QK reads first.
    __syncthreads();

    // stage O (row q = wid*16+l15, cols j*16+quad*4+r) into Pls, swizzled
    bf16_t* orow = Pls + (wid * 16 + l15) * LDSW;
    #pragma unroll
    for (int jp = 0; jp < 4; jp++) {
        union { bf16_t h[4]; unsigned long long u; } pk;
        pk.h[0] = (bf16_t)(oacc[jp][0] * inv);
        pk.h[1] = (bf16_t)(oacc[jp][1] * inv);
        pk.h[2] = (bf16_t)(oacc[jp][2] * inv);
        pk.h[3] = (bf16_t)(oacc[jp][3] * inv);
        const int Lc = jp * 2 + (quad >> 1);         // logical 16B chunk
        *reinterpret_cast<unsigned long long*>(
            orow + ((Lc ^ s7) << 3) + ((quad & 1) << 2)) = pk.u;
    }
    __syncthreads();

    const int b = bh >> 4, h = bh & 15;
    #pragma unroll
    for (int c = tid; c < 512; c += 256) {   // 64 rows x 8 chunks of 8 bf16
        int row = c >> 3, chunk = c & 7;
        uint4 val = *reinterpret_cast<const uint4*>(
            Pls + row * LDSW + ((chunk ^ (row & 7)) << 3));
        *reinterpret_cast<uint4*>(Oc + ((size_t)(b * SEQ + q0 + row)) * D_MODEL + h * DK + (chunk << 3)) = val;
    }
}

extern "C" void kernel_launch(void* const* d_in, const int* in_sizes, int n_in,
                              void* d_out, int out_size, void* d_ws, size_t ws_size,
                              hipStream_t stream) {
    const float* q  = (const float*)d_in[0];
    const float* k  = (const float*)d_in[1];
    const float* v  = (const float*)d_in[2];
    const float* Wq = (const float*)d_in[3];
    const float* bq = (const float*)d_in[4];
    const float* Wk = (const float*)d_in[5];
    const float* bk = (const float*)d_in[6];
    const float* Wv = (const float*)d_in[7];
    const float* bv = (const float*)d_in[8];
    const float* Wo = (const float*)d_in[9];
    const float* bo = (const float*)d_in[10];

    const size_t nx = (size_t)MROWS * D_MODEL;   // 4,194,304
    const size_t nw = (size_t)D_MODEL * D_MODEL; // 1,048,576

    bf16_t* qb  = (bf16_t*)d_ws;
    bf16_t* kb  = qb  + nx;
    bf16_t* vb  = kb  + nx;
    bf16_t* Wqb = vb  + nx;
    bf16_t* Wkb = Wqb + nw;
    bf16_t* Wvb = Wkb + nw;
    bf16_t* Wob = Wvb + nw;
    bf16_t* Qh  = Wob + nw;   // [BH][S][DK]
    bf16_t* Kh  = Qh  + nx;   // [BH][S][DK]
    bf16_t* Vt  = Kh  + nx;   // [BH][DK][S]
    bf16_t* Oc  = Vt  + nx;   // [B*S][D]

    pack7<<<dim3(2048, 7), 256, 0, stream>>>(q, k, v, Wq, Wk, Wv, Wo,
                                             qb, kb, vb, Wqb, Wkb, Wvb, Wob);

    proj_gemm<<<dim3(8, 32, 3), 256, 0, stream>>>(qb, kb, vb, Wqb, Wkb, Wvb, bq, bk, bv, Qh, Kh, Vt);
    attn_kernel<<<dim3(32, 32), 256, 0, stream>>>(Qh, Kh, Vt, Oc);
    out_gemm<<<dim3(8, 64), 256, 0, stream>>>(Oc, Wob, bo, (float*)d_out);
}

// Round 8
// 220.427 us; speedup vs baseline: 1.1865x; 1.0107x over previous
//
#include <hip/hip_runtime.h>
#include <hip/hip_bf16.h>
#include <math.h>

// ---- types ----
typedef __bf16 bf16_t;
typedef bf16_t bf16x8 __attribute__((ext_vector_type(8)));
typedef float f32x4 __attribute__((ext_vector_type(4)));

#define D_MODEL 1024
#define NH 16
#define DK 64
#define SEQ 2048
#define MROWS 4096   // B*S
#define LDSW 64      // UNPADDED row width for async-DMA tiles (XOR-swizzled)
#define LDC 136      // padded row for the 128x128 epilogue staging tile

__device__ __forceinline__ bf16x8 ldfrag(const bf16_t* p) {
    union { uint4 u; bf16x8 v; } c;
    c.u = *reinterpret_cast<const uint4*>(p);
    return c.v;
}

__device__ __forceinline__ f32x4 zero4() { f32x4 z = {0.f, 0.f, 0.f, 0.f}; return z; }

// async global->LDS DMA, 16B per lane. LDS dest = wave-uniform base + lane*16.
__device__ __forceinline__ void gll16(const bf16_t* g, bf16_t* l) {
    __builtin_amdgcn_global_load_lds(
        (const __attribute__((address_space(1))) unsigned int*)g,
        (__attribute__((address_space(3))) unsigned int*)l,
        16, 0, 0);
}

// ---- fp32 -> bf16 pack, all 7 tensors in one launch; 8 floats/thread ----
__global__ void pack7(const float* __restrict__ q, const float* __restrict__ k,
                      const float* __restrict__ v, const float* __restrict__ wq,
                      const float* __restrict__ wk, const float* __restrict__ wv,
                      const float* __restrict__ wo,
                      bf16_t* __restrict__ dq, bf16_t* __restrict__ dk,
                      bf16_t* __restrict__ dv, bf16_t* __restrict__ dwq,
                      bf16_t* __restrict__ dwk, bf16_t* __restrict__ dwv,
                      bf16_t* __restrict__ dwo) {
    const int y = blockIdx.y;
    if (y >= 3 && blockIdx.x >= 512) return;   // weights are 1/4 the size
    const float* s;
    bf16_t* d;
    switch (y) {
        case 0: s = q;  d = dq;  break;
        case 1: s = k;  d = dk;  break;
        case 2: s = v;  d = dv;  break;
        case 3: s = wq; d = dwq; break;
        case 4: s = wk; d = dwk; break;
        case 5: s = wv; d = dwv; break;
        default: s = wo; d = dwo; break;
    }
    int i = (blockIdx.x * blockDim.x + threadIdx.x) * 8;
    float4 f0 = *reinterpret_cast<const float4*>(s + i);
    float4 f1 = *reinterpret_cast<const float4*>(s + i + 4);
    union { bf16_t h[8]; uint4 u; } o;
    o.h[0] = (bf16_t)f0.x; o.h[1] = (bf16_t)f0.y; o.h[2] = (bf16_t)f0.z; o.h[3] = (bf16_t)f0.w;
    o.h[4] = (bf16_t)f1.x; o.h[5] = (bf16_t)f1.y; o.h[6] = (bf16_t)f1.z; o.h[7] = (bf16_t)f1.w;
    *reinterpret_cast<uint4*>(d + i) = o.u;
}

// ---- shared GEMM core: C(128x128) = A(rowmaj MxK) * B(rowmaj NxK)^T ----
// m97 structure: async global_load_lds staging; unpadded [128][64] tiles with
// XOR 16B-chunk swizzle (phys chunk p of row r holds logical chunk p^(r&7)).
__device__ __forceinline__ void gemm_core(
    const bf16_t* __restrict__ A, const bf16_t* __restrict__ Bm,
    int K, int m0, int n0,
    bf16_t* As, bf16_t* Bs,       // each 128*LDSW bf16
    f32x4 acc[4][4]) {

    const int tid = threadIdx.x;
    const int lane = tid & 63;
    const int wid = tid >> 6;
    const int wm = (wid >> 1) * 64, wn = (wid & 1) * 64;
    const int l15 = lane & 15, quad = lane >> 4;

    const int lrow   = lane >> 3;                // 0..7 row within 8-row group
    const int gcol   = ((lane & 7) ^ lrow) * 8;  // swizzled logical col (elems)

    #pragma unroll
    for (int i = 0; i < 4; i++)
        #pragma unroll
        for (int j = 0; j < 4; j++) acc[i][j] = zero4();

    for (int k0 = 0; k0 < K; k0 += 64) {
        __syncthreads();
        #pragma unroll
        for (int t = 0; t < 4; t++) {
            const int rbase = wid * 32 + t * 8;
            gll16(A  + (size_t)(m0 + rbase + lrow) * K + k0 + gcol, As + rbase * LDSW);
            gll16(Bm + (size_t)(n0 + rbase + lrow) * K + k0 + gcol, Bs + rbase * LDSW);
        }
        __syncthreads();
        #pragma unroll
        for (int c = 0; c < 2; c++) {
            bf16x8 af[4], bfr[4];
            #pragma unroll
            for (int i = 0; i < 4; i++) {
                const int row = wm + i * 16 + l15;
                const int pc = ((c * 4 + quad) ^ (l15 & 7)) * 8;
                af[i] = ldfrag(As + row * LDSW + pc);
            }
            #pragma unroll
            for (int j = 0; j < 4; j++) {
                const int row = wn + j * 16 + l15;
                const int pc = ((c * 4 + quad) ^ (l15 & 7)) * 8;
                bfr[j] = ldfrag(Bs + row * LDSW + pc);
            }
            #pragma unroll
            for (int i = 0; i < 4; i++)
                #pragma unroll
                for (int j = 0; j < 4; j++)
                    acc[i][j] = __builtin_amdgcn_mfma_f32_16x16x32_bf16(af[i], bfr[j], acc[i][j], 0, 0, 0);
        }
    }
}

// ---- fused Q/K/V projection: blockIdx.z picks which ----
__global__ __launch_bounds__(256, 3) void proj_gemm(
    const bf16_t* __restrict__ qb, const bf16_t* __restrict__ kb,
    const bf16_t* __restrict__ vb,
    const bf16_t* __restrict__ Wq, const bf16_t* __restrict__ Wk,
    const bf16_t* __restrict__ Wv,
    const float* __restrict__ bq, const float* __restrict__ bk, const float* __restrict__ bv,
    bf16_t* __restrict__ Qh, bf16_t* __restrict__ Kh, bf16_t* __restrict__ Vt) {

    __shared__ __align__(16) bf16_t sm[128 * LDC];   // 34816B: As|Bs, reused as Cs
    bf16_t* As = sm;
    bf16_t* Bs = sm + 128 * LDSW;
    bf16_t (*Cs)[LDC] = reinterpret_cast<bf16_t(*)[LDC]>(sm);
    f32x4 acc[4][4];

    const int mode = blockIdx.z;
    const bf16_t* X = (mode == 0) ? qb : (mode == 1) ? kb : vb;
    const bf16_t* W = (mode == 0) ? Wq : (mode == 1) ? Wk : Wv;
    const float* bias = (mode == 0) ? bq : (mode == 1) ? bk : bv;
    const int m0 = blockIdx.y * 128, n0 = blockIdx.x * 128;

    gemm_core(X, W, D_MODEL, m0, n0, As, Bs, acc);

    const int tid = threadIdx.x, lane = tid & 63, wid = tid >> 6;
    const int wm = (wid >> 1) * 64, wn = (wid & 1) * 64;
    const int l15 = lane & 15, quad = lane >> 4;

    __syncthreads();
    if (mode != 2) {
        // Q gets 1/sqrt(dk) * log2(e) folded in so attn can use raw exp2
        const float sc = (mode == 0) ? 0.125f * 1.44269504f : 1.0f;
        #pragma unroll
        for (int i = 0; i < 4; i++)
            #pragma unroll
            for (int j = 0; j < 4; j++)
                #pragma unroll
                for (int r = 0; r < 4; r++) {
                    int gn = n0 + wn + j * 16 + l15;
                    Cs[wm + i * 16 + quad * 4 + r][wn + j * 16 + l15] =
                        (bf16_t)((acc[i][j][r] + bias[gn]) * sc);
                }
    } else {
        #pragma unroll
        for (int i = 0; i < 4; i++)
            #pragma unroll
            for (int j = 0; j < 4; j++)
                #pragma unroll
                for (int r = 0; r < 4; r++) {
                    int gn = n0 + wn + j * 16 + l15;
                    Cs[wn + j * 16 + l15][wm + i * 16 + quad * 4 + r] =
                        (bf16_t)(acc[i][j][r] + bias[gn]);
                }
    }
    __syncthreads();

    #pragma unroll
    for (int c = tid; c < 2048; c += 256) {
        int row = c >> 4, col8 = (c & 15) << 3;
        uint4 val = *reinterpret_cast<const uint4*>(&Cs[row][col8]);
        if (mode != 2) {
            int gm = m0 + row, gn = n0 + col8;
            int b = gm >> 11, seq = gm & 2047;
            int h = gn >> 6, dk = gn & 63;
            bf16_t* dst = (mode == 0) ? Qh : Kh;
            *reinterpret_cast<uint4*>(dst + ((size_t)(b * NH + h) * SEQ + seq) * DK + dk) = val;
        } else {
            int gn = n0 + row, gm = m0 + col8;
            int b = gm >> 11, seq = gm & 2047;
            int h = gn >> 6, dk = gn & 63;
            *reinterpret_cast<uint4*>(Vt + ((size_t)(b * NH + h) * DK + dk) * SEQ + seq) = val;
        }
    }
}

// ---- output projection: 64x128 tiles for TLP ----
__global__ __launch_bounds__(256, 2) void out_gemm(
    const bf16_t* __restrict__ Oc, const bf16_t* __restrict__ Wo,
    const float* __restrict__ bo, float* __restrict__ Cout) {

    __shared__ __align__(16) bf16_t As[64 * LDSW];    // 64 M-rows
    __shared__ __align__(16) bf16_t Bs[128 * LDSW];   // 128 N-rows
    f32x4 acc[2][4];
    const int m0 = blockIdx.y * 64, n0 = blockIdx.x * 128;

    const int tid = threadIdx.x;
    const int lane = tid & 63;
    const int wid = tid >> 6;
    const int wm = (wid >> 1) * 32, wn = (wid & 1) * 64;
    const int l15 = lane & 15, quad = lane >> 4;
    const int lrow = lane >> 3;
    const int gcol = ((lane & 7) ^ lrow) * 8;

    #pragma unroll
    for (int i = 0; i < 2; i++)
        #pragma unroll
        for (int j = 0; j < 4; j++) acc[i][j] = zero4();

    for (int k0 = 0; k0 < D_MODEL; k0 += 64) {
        __syncthreads();
        // A: 64 rows -> 2 gll16/wave; B: 128 rows -> 4 gll16/wave
        #pragma unroll
        for (int t = 0; t < 2; t++) {
            const int rbase = wid * 16 + t * 8;
            gll16(Oc + (size_t)(m0 + rbase + lrow) * D_MODEL + k0 + gcol, As + rbase * LDSW);
        }
        #pragma unroll
        for (int t = 0; t < 4; t++) {
            const int rbase = wid * 32 + t * 8;
            gll16(Wo + (size_t)(n0 + rbase + lrow) * D_MODEL + k0 + gcol, Bs + rbase * LDSW);
        }
        __syncthreads();
        #pragma unroll
        for (int c = 0; c < 2; c++) {
            bf16x8 af[2], bfr[4];
            #pragma unroll
            for (int i = 0; i < 2; i++) {
                const int row = wm + i * 16 + l15;
                const int pc = ((c * 4 + quad) ^ (l15 & 7)) * 8;
                af[i] = ldfrag(As + row * LDSW + pc);
            }
            #pragma unroll
            for (int j = 0; j < 4; j++) {
                const int row = wn + j * 16 + l15;
                const int pc = ((c * 4 + quad) ^ (l15 & 7)) * 8;
                bfr[j] = ldfrag(Bs + row * LDSW + pc);
            }
            #pragma unroll
            for (int i = 0; i < 2; i++)
                #pragma unroll
                for (int j = 0; j < 4; j++)
                    acc[i][j] = __builtin_amdgcn_mfma_f32_16x16x32_bf16(af[i], bfr[j], acc[i][j], 0, 0, 0);
        }
    }

    #pragma unroll
    for (int i = 0; i < 2; i++)
        #pragma unroll
        for (int j = 0; j < 4; j++)
            #pragma unroll
            for (int r = 0; r < 4; r++) {
                int gm = m0 + wm + i * 16 + quad * 4 + r;
                int gn = n0 + wn + j * 16 + l15;
                Cout[(size_t)gm * D_MODEL + gn] = acc[i][j][r] + bo[gn];
            }
}

// ---- flash attention: one block = one (b,h) x 128-query tile ----
// R17 = R16 (KVBLK=128, zero-shuffle PV, sigma-permuted K) with QBLK 64->128:
// 512 threads / 8 waves. Per-wave compute identical (16q x 128k); per-wave
// staging HALVES (2+2 gll16 vs 4+4) and each (b,h)'s K/V is staged 16x
// instead of 32x (L2 re-read traffic halves: 128->64 KB/iter/CU). Grid
// (32,16) = 512 blocks = 2/CU x 8 waves = 16 waves/CU (unchanged). LDS
// 32 KB; O-epilogue (128x64 = 16 KB) aliases Ks exactly. Pre-committed
// risk: barrier couples 8 waves with only 2 independent blocks/CU; if attn
// >= 70 µs, revert to R16 attn and move to the GEMM side.
__global__ __launch_bounds__(512, 4) void attn_kernel(
    const bf16_t* __restrict__ Qh, const bf16_t* __restrict__ Kh,
    const bf16_t* __restrict__ Vt, bf16_t* __restrict__ Oc) {

    __shared__ __align__(16) bf16_t sma[16384];       // 32 KB
    bf16_t* Ks  = sma;                                // [128][64], sigma rows, chunk^(row&7)
    bf16_t* Vts = sma + 128 * 64;                     // [64][128], chunk^(row&15)
    bf16_t* Pls = sma;                                // O epilogue [128][64] (aliases Ks)

    const int tid = threadIdx.x, lane = tid & 63, wid = tid >> 6;   // wid 0..7
    const int l15 = lane & 15, quad = lane >> 4;
    const int bh = blockIdx.x;                 // XCD-friendly
    const int q0 = blockIdx.y * 128;
    const bf16_t* Qbase = Qh + (size_t)bh * SEQ * DK;
    const bf16_t* Kbase = Kh + (size_t)bh * SEQ * DK;
    const bf16_t* Vbase = Vt + (size_t)bh * DK * SEQ;

    const int lrow = lane >> 3;                  // 0..7 row within 8-row group
    const int gcol = ((lane & 7) ^ lrow) * 8;    // K swizzled col (elems)

    // Q fragments: wave wid owns query rows [q0+wid*16, +16)
    bf16x8 aQ[2];
    #pragma unroll
    for (int c = 0; c < 2; c++)
        aQ[c] = ldfrag(Qbase + (size_t)(q0 + wid * 16 + l15) * DK + c * 32 + quad * 8);

    f32x4 oacc[4];
    #pragma unroll
    for (int j = 0; j < 4; j++) oacc[j] = zero4();
    float l_acc = 0.f;

    const int s7 = l15 & 7;
    const int vlrow = lane >> 4;                 // V staging: row within 4-row group
    const int vchk0 = lane & 15;                 // V staging: phys chunk

    for (int kt = 0; kt < SEQ / 128; kt++) {
        const int k0 = kt * 128;
        __syncthreads();   // prev-iter reads of Ks/Vts done
        // K: 128 sigma-permuted rows of 64 (2 gll16/wave over 8 waves);
        // V^T: 64 rows of 128, key-chunk pre-swizzled (2 gll16/wave)
        #pragma unroll
        for (int t = 0; t < 2; t++) {
            const int rbase = wid * 16 + t * 8;  // 0..127 step 8
            const int srow = rbase + lrow;       // tile slot 0..127
            const int sigma = ((srow >> 5) << 5) | (((srow >> 2) & 3) << 3) |
                              (((srow >> 4) & 1) << 2) | (srow & 3);
            gll16(Kbase + (size_t)(k0 + sigma) * DK + gcol, Ks + rbase * 64);

            const int vrb = wid * 8 + t * 4;     // V^T row base (dk), 0..63 step 4
            const int vrow = vrb + vlrow;        // 0..63
            gll16(Vbase + (size_t)vrow * SEQ + k0 + ((vchk0 ^ (vrow & 15)) << 3),
                  Vts + vrb * 128);
        }
        __syncthreads();   // barrier drains vmcnt -> DMA complete

        // S^T = K*Q^T (Q pre-scaled by log2e/8); slots sigma-ordered.
        // sacc[j][r] = S[slot j*16+quad*4+r][q = q0+wid*16+l15]
        f32x4 sacc[8];
        #pragma unroll
        for (int j = 0; j < 8; j++) sacc[j] = zero4();
        #pragma unroll
        for (int c = 0; c < 2; c++) {
            bf16x8 bk4[8];
            #pragma unroll
            for (int j = 0; j < 8; j++) {
                const int pc = ((c * 4 + quad) ^ s7) * 8;
                bk4[j] = ldfrag(Ks + (j * 16 + l15) * 64 + pc);
            }
            #pragma unroll
            for (int j = 0; j < 8; j++)
                sacc[j] = __builtin_amdgcn_mfma_f32_16x16x32_bf16(
                    bk4[j], aQ[c], sacc[j], 0, 0, 0);
        }

        // exp2 + row-sum + in-register P^T fragments (no LDS):
        // pb[c] element 4h+r = exp2(sacc[2c+h][r]) = P[key k0+32c+8quad+4h+r]
        bf16x8 pb[4];
        #pragma unroll
        for (int c = 0; c < 4; c++) {
            union { bf16_t h[8]; bf16x8 v; } pk;
            #pragma unroll
            for (int half = 0; half < 2; half++) {
                const int j = c * 2 + half;
                float e0 = exp2f(sacc[j][0]);
                float e1 = exp2f(sacc[j][1]);
                float e2 = exp2f(sacc[j][2]);
                float e3 = exp2f(sacc[j][3]);
                l_acc += (e0 + e1) + (e2 + e3);
                pk.h[half * 4 + 0] = (bf16_t)e0;
                pk.h[half * 4 + 1] = (bf16_t)e1;
                pk.h[half * 4 + 2] = (bf16_t)e2;
                pk.h[half * 4 + 3] = (bf16_t)e3;
            }
            pb[c] = pk.v;
        }

        // O^T += V^T * P^T : A = V^T fragment (rows d = j*16+l15, key chunk
        // (c*4+quad)^l15), B = pb[c]. oacc[j][r] = O[q=l15][d=j*16+quad*4+r]
        #pragma unroll
        for (int c = 0; c < 4; c++) {
            bf16x8 av[4];
            #pragma unroll
            for (int j = 0; j < 4; j++) {
                const int pc = ((c * 4 + quad) ^ l15) * 8;
                av[j] = ldfrag(Vts + (j * 16 + l15) * 128 + pc);
            }
            #pragma unroll
            for (int j = 0; j < 4; j++)
                oacc[j] = __builtin_amdgcn_mfma_f32_16x16x32_bf16(
                    av[j], pb[c], oacc[j], 0, 0, 0);
        }
    }

    // normalize: l_acc is the partial sum for q=l15 over this quad's keys;
    // reduce across quads. inv is lane-local (this lane's own q).
    float l = l_acc;
    l += __shfl_xor(l, 16, 64);
    l += __shfl_xor(l, 32, 64);
    const float inv = 1.0f / l;

    // Pls aliases Ks: every wave must be past its last QK reads first.
    __syncthreads();

    // stage O (row q = wid*16+l15, cols j*16+quad*4+r) into Pls, swizzled
    bf16_t* orow = Pls + (wid * 16 + l15) * LDSW;
    #pragma unroll
    for (int jp = 0; jp < 4; jp++) {
        union { bf16_t h[4]; unsigned long long u; } pk;
        pk.h[0] = (bf16_t)(oacc[jp][0] * inv);
        pk.h[1] = (bf16_t)(oacc[jp][1] * inv);
        pk.h[2] = (bf16_t)(oacc[jp][2] * inv);
        pk.h[3] = (bf16_t)(oacc[jp][3] * inv);
        const int Lc = jp * 2 + (quad >> 1);         // logical 16B chunk
        *reinterpret_cast<unsigned long long*>(
            orow + ((Lc ^ s7) << 3) + ((quad & 1) << 2)) = pk.u;
    }
    __syncthreads();

    const int b = bh >> 4, h = bh & 15;
    #pragma unroll
    for (int c = tid; c < 1024; c += 512) {  // 128 rows x 8 chunks of 8 bf16
        int row = c >> 3, chunk = c & 7;
        uint4 val = *reinterpret_cast<const uint4*>(
            Pls + row * LDSW + ((chunk ^ (row & 7)) << 3));
        *reinterpret_cast<uint4*>(Oc + ((size_t)(b * SEQ + q0 + row)) * D_MODEL + h * DK + (chunk << 3)) = val;
    }
}

extern "C" void kernel_launch(void* const* d_in, const int* in_sizes, int n_in,
                              void* d_out, int out_size, void* d_ws, size_t ws_size,
                              hipStream_t stream) {
    const float* q  = (const float*)d_in[0];
    const float* k  = (const float*)d_in[1];
    const float* v  = (const float*)d_in[2];
    const float* Wq = (const float*)d_in[3];
    const float* bq = (const float*)d_in[4];
    const float* Wk = (const float*)d_in[5];
    const float* bk = (const float*)d_in[6];
    const float* Wv = (const float*)d_in[7];
    const float* bv = (const float*)d_in[8];
    const float* Wo = (const float*)d_in[9];
    const float* bo = (const float*)d_in[10];

    const size_t nx = (size_t)MROWS * D_MODEL;   // 4,194,304
    const size_t nw = (size_t)D_MODEL * D_MODEL; // 1,048,576

    bf16_t* qb  = (bf16_t*)d_ws;
    bf16_t* kb  = qb  + nx;
    bf16_t* vb  = kb  + nx;
    bf16_t* Wqb = vb  + nx;
    bf16_t* Wkb = Wqb + nw;
    bf16_t* Wvb = Wkb + nw;
    bf16_t* Wob = Wvb + nw;
    bf16_t* Qh  = Wob + nw;   // [BH][S][DK]
    bf16_t* Kh  = Qh  + nx;   // [BH][S][DK]
    bf16_t* Vt  = Kh  + nx;   // [BH][DK][S]
    bf16_t* Oc  = Vt  + nx;   // [B*S][D]

    pack7<<<dim3(2048, 7), 256, 0, stream>>>(q, k, v, Wq, Wk, Wv, Wo,
                                             qb, kb, vb, Wqb, Wkb, Wvb, Wob);

    proj_gemm<<<dim3(8, 32, 3), 256, 0, stream>>>(qb, kb, vb, Wqb, Wkb, Wvb, bq, bk, bv, Qh, Kh, Vt);
    attn_kernel<<<dim3(32, 16), 512, 0, stream>>>(Qh, Kh, Vt, Oc);
    out_gemm<<<dim3(8, 64), 256, 0, stream>>>(Oc, Wob, bo, (float*)d_out);
}